// Round 4
// baseline (709.175 us; speedup 1.0000x reference)
//
#include <hip/hip_runtime.h>
#include <hip/hip_bf16.h>

typedef unsigned short u16;
typedef __attribute__((ext_vector_type(8))) short bf16x8;
typedef __attribute__((ext_vector_type(4))) float f32x4;

#define T_TOK 16384
#define H_DIM 2048
#define F_DIM 4096
#define E_NUM 8
#define CAPX  2048   // tokens per expert

__device__ __forceinline__ unsigned cvt2(float a, float b) {
    __hip_bfloat162 h = __float22bfloat162_rn(make_float2(a, b));
    union { __hip_bfloat162 h; unsigned u; } c; c.h = h; return c.u;
}
__device__ __forceinline__ u16 f2bf(float f) {
    __hip_bfloat16 h = __float2bfloat16(f);
    union { __hip_bfloat16 h; u16 u; } c; c.h = h; return c.u;
}
__device__ __forceinline__ float gelu_tanh(float x) {
    float x3 = x * x * x;
    float z = 0.7978845608028654f * (x + 0.044715f * x3);
    float e = __expf(2.0f * z);
    float t = 1.0f - 2.0f / (e + 1.0f);   // tanh(z)
    return 0.5f * x * (1.0f + t);
}

__device__ __forceinline__ void gload_lds16(const void* g, void* l) {
    __builtin_amdgcn_global_load_lds(
        (const __attribute__((address_space(1))) void*)g,
        (__attribute__((address_space(3))) void*)l,
        16, 0, 0);
}

// ---------------------------------------------------------------------------
// f32 -> bf16 conversion pre-pass
// ---------------------------------------------------------------------------
__global__ void cvt_f32_bf16(const float* __restrict__ in, u16* __restrict__ out,
                             long n) {
    long i = (((long)blockIdx.x * blockDim.x) + threadIdx.x) << 3;
    const long stride = ((long)gridDim.x * blockDim.x) << 3;
    for (; i < n; i += stride) {
        float4 v0 = *(const float4*)(in + i);
        float4 v1 = *(const float4*)(in + i + 4);
        uint4 pk;
        pk.x = cvt2(v0.x, v0.y); pk.y = cvt2(v0.z, v0.w);
        pk.z = cvt2(v1.x, v1.y); pk.w = cvt2(v1.z, v1.w);
        *(uint4*)(out + i) = pk;
    }
}

// ---------------------------------------------------------------------------
// 256x256 8-phase bf16 NT GEMM with one-phase-lookahead ds_reads.
// C[M,N] = A[M,K] @ B[N,K]^T per expert.
// 512 thr = 8 waves (2M x 4N); per-wave 128x64 out = acc[8][4] f32x4.
// BK=64 as 2 K-halves of 32; LDS = 2buf x (A 32K + B 32K) = 128 KiB.
// Stage rotation (iter = tiles t->buf0, t+1->buf1), stages per phase:
//   p1:A1(t+1)  p2:B0(t+2) p3:A0(t+2) p4:B1(t+2)+vmcnt(6)
//   p5:A1(t+2)  p6:B0(t+3) p7:A0(t+3) p8:B1(t+3)+vmcnt(6)
// ds_reads in phase p load the frags consumed by phase p+1 (ping-pong reg
// sets). Buffer-crossing reads (p4: buf1, p8: next buf0) sit AFTER
// vmcnt(6)+barrier so all waves' stages have landed. Every stage's target
// slot had its readers complete >=1 barrier before the stage issues.
// Swizzle: 16B-slot' = slot ^ ((row>>1)&3), both sides (rule 21).
// ---------------------------------------------------------------------------
template<bool GELU_BF16_OUT>
__global__ __launch_bounds__(512, 2)
void gemm8p(const u16* __restrict__ A, const u16* __restrict__ B,
            void* __restrict__ Cv, int Mpe, int N, int K,
            int mtpe, int ntpe) {
    __shared__ uint4 lds4[8192];          // 128 KiB
    char* ldsb = (char*)lds4;

    const int tid  = threadIdx.x;
    const int lane = tid & 63;
    const int wid  = tid >> 6;
    const int wm   = wid >> 2;            // 0..1
    const int wn   = wid & 3;             // 0..3
    const int lr   = lane & 15;

    // XCD-aware bijective swizzle (grid % 8 == 0)
    const int nwg = gridDim.x;
    const int cpx = nwg >> 3;
    const int bid = blockIdx.x;
    const int wg  = (bid & 7) * cpx + (bid >> 3);

    const int tpe = mtpe * ntpe;
    const int e   = wg / tpe;
    const int rem = wg - e * tpe;
    const int mt  = rem / ntpe;
    const int nt  = rem - mt * ntpe;

    const u16* Abase = A + (size_t)e * Mpe * K + (size_t)mt * 256 * K;
    const u16* Bbase = B + (size_t)e * N   * K + (size_t)nt * 256 * K;

    // staging pointers (bytes); row = tid>>2 (+128), pre-swizzled source slot
    const int srow = tid >> 2;
    const int sx   = (tid & 3) ^ ((tid >> 3) & 3);
    const char* pA0 = (const char*)(Abase + (size_t)srow * K + sx * 8);
    const char* pA1 = (const char*)(Abase + (size_t)(srow + 128) * K + sx * 8);
    const char* pB0 = (const char*)(Bbase + (size_t)srow * K + sx * 8);
    const char* pB1 = (const char*)(Bbase + (size_t)(srow + 128) * K + sx * 8);
    char* ldsw = ldsb + (wid << 10);

    // read-side per-thread byte offsets (swizzled slot)
    const int slotp = (((lane >> 4) ^ ((lr >> 1) & 3)) << 4);
    const int aoffb = ((wm * 128 + lr) << 6) + slotp;
    const int boffb = ((wn * 64  + lr) << 6) + slotp;

    const int NT = K >> 6;   // K-tiles (even)

    f32x4 acc[8][4] = {};
    bf16x8 afA[4], afB[4], bfA[4], bfB[4];

#define STAGE_A(KH, BUF, DOFF) do {                                           \
    char* d_ = ldsw + (BUF) * 32768 + (KH) * 16384;                           \
    gload_lds16(pA0 + (DOFF) + (KH) * 64, d_);                                \
    gload_lds16(pA1 + (DOFF) + (KH) * 64, d_ + 8192);                         \
} while (0)

#define STAGE_B(KH, BUF, DOFF) do {                                           \
    char* d_ = ldsw + 65536 + (BUF) * 32768 + (KH) * 16384;                   \
    gload_lds16(pB0 + (DOFF) + (KH) * 64, d_);                                \
    gload_lds16(pB1 + (DOFF) + (KH) * 64, d_ + 8192);                         \
} while (0)

#define READ_A(DST, BUF, KS, MH) do {                                         \
    const char* ab_ = ldsb + (BUF) * 32768 + (KS) * 16384 + (MH) * 4096 + aoffb; \
    DST[0] = *(const bf16x8*)(ab_);                                           \
    DST[1] = *(const bf16x8*)(ab_ + 1024);                                    \
    DST[2] = *(const bf16x8*)(ab_ + 2048);                                    \
    DST[3] = *(const bf16x8*)(ab_ + 3072);                                    \
} while (0)

#define READ_B(DST, BUF, KS) do {                                             \
    const char* bb_ = ldsb + 65536 + (BUF) * 32768 + (KS) * 16384 + boffb;    \
    DST[0] = *(const bf16x8*)(bb_);                                           \
    DST[1] = *(const bf16x8*)(bb_ + 1024);                                    \
    DST[2] = *(const bf16x8*)(bb_ + 2048);                                    \
    DST[3] = *(const bf16x8*)(bb_ + 3072);                                    \
} while (0)

#define BAR1() do { __builtin_amdgcn_s_barrier();                             \
                    __builtin_amdgcn_sched_barrier(0); } while (0)
#define BAR2() do { __builtin_amdgcn_sched_barrier(0);                        \
                    __builtin_amdgcn_s_barrier(); } while (0)
#define VM6()  asm volatile("s_waitcnt vmcnt(6)" ::: "memory")

#define MFMA16(AF, BF, MH) do {                                               \
    __builtin_amdgcn_s_setprio(1);                                            \
    _Pragma("unroll")                                                         \
    for (int i_ = 0; i_ < 4; ++i_) {                                          \
        _Pragma("unroll")                                                     \
        for (int n_ = 0; n_ < 4; ++n_)                                        \
            acc[(MH)*4 + i_][n_] = __builtin_amdgcn_mfma_f32_16x16x32_bf16(   \
                AF[i_], BF[n_], acc[(MH)*4 + i_][n_], 0, 0, 0);               \
    }                                                                         \
    __builtin_amdgcn_s_setprio(0);                                            \
} while (0)

// Phase p's region also loads frags for phase p+1 (lookahead).
#define ITER(D1, D2, D3) do {                                                  \
    /*p1*/ STAGE_A(1,1,(D1)); READ_A(afB,0,0,1);                               \
           BAR1(); MFMA16(afA,bfA,0); BAR2();                                  \
    /*p2*/ STAGE_B(0,0,(D2)); READ_A(afA,0,1,0); READ_B(bfB,0,1);              \
           BAR1(); MFMA16(afB,bfA,1); BAR2();                                  \
    /*p3*/ STAGE_A(0,0,(D2)); READ_A(afB,0,1,1);                               \
           BAR1(); MFMA16(afA,bfB,0); BAR2();                                  \
    /*p4*/ STAGE_B(1,0,(D2)); VM6();                                           \
           BAR1(); READ_A(afA,1,0,0); READ_B(bfA,1,0);                         \
           MFMA16(afB,bfB,1); BAR2();                                          \
    /*p5*/ STAGE_A(1,0,(D2)); READ_A(afB,1,0,1);                               \
           BAR1(); MFMA16(afA,bfA,0); BAR2();                                  \
    /*p6*/ STAGE_B(0,1,(D3)); READ_A(afA,1,1,0); READ_B(bfB,1,1);              \
           BAR1(); MFMA16(afB,bfA,1); BAR2();                                  \
    /*p7*/ STAGE_A(0,1,(D3)); READ_A(afB,1,1,1);                               \
           BAR1(); MFMA16(afA,bfB,0); BAR2();                                  \
    /*p8*/ STAGE_B(1,1,(D3)); VM6();                                           \
           BAR1(); READ_A(afA,0,0,0); READ_B(bfA,0,0);                         \
           MFMA16(afB,bfB,1); BAR2();                                          \
} while (0)

    // prologue: 7 half-tiles; vmcnt(6) => tile0 (4 halves) landed
    STAGE_B(0, 0, 0);
    STAGE_A(0, 0, 0);
    STAGE_B(1, 0, 0);
    STAGE_A(1, 0, 0);
    STAGE_B(0, 1, 128);
    STAGE_A(0, 1, 128);
    STAGE_B(1, 1, 128);
    VM6();
    __builtin_amdgcn_s_barrier();
    __builtin_amdgcn_sched_barrier(0);
    READ_A(afA, 0, 0, 0);
    READ_B(bfA, 0, 0);

    const int nmain = (NT >> 1) - 1;
    for (int it = 0; it < nmain; ++it) {
        ITER(128, 256, 384);
        pA0 += 256; pA1 += 256; pB0 += 256; pB1 += 256;
    }
    // peeled last iteration: p1's stage (t+1) still real; t+2/t+3 stages are
    // dead -> clamp to delta 0 (valid addresses, slots never consumed).
    ITER(128, 0, 0);

#undef STAGE_A
#undef STAGE_B
#undef READ_A
#undef READ_B
#undef BAR1
#undef BAR2
#undef VM6
#undef MFMA16
#undef ITER

    // epilogue: C/D layout col = lane&15, row = (lane>>4)*4 + reg
    const int r0 = (lane >> 4) << 2;
    if constexpr (GELU_BF16_OUT) {
        u16* Cb = (u16*)Cv;
        #pragma unroll
        for (int m = 0; m < 8; ++m)
            #pragma unroll
            for (int n = 0; n < 4; ++n) {
                const int col = nt * 256 + wn * 64 + n * 16 + lr;
                #pragma unroll
                for (int j = 0; j < 4; ++j) {
                    const int row = mt * 256 + wm * 128 + m * 16 + r0 + j;
                    Cb[((size_t)e * Mpe + row) * N + col] =
                        f2bf(gelu_tanh(acc[m][n][j]));
                }
            }
    } else {
        float* Cf = (float*)Cv;
        #pragma unroll
        for (int m = 0; m < 8; ++m)
            #pragma unroll
            for (int n = 0; n < 4; ++n) {
                const int col = nt * 256 + wn * 64 + n * 16 + lr;
                #pragma unroll
                for (int j = 0; j < 4; ++j) {
                    const int row = mt * 256 + wm * 128 + m * 16 + r0 + j;
                    Cf[((size_t)e * Mpe + row) * N + col] = acc[m][n][j];
                }
            }
    }
}

// ---------------------------------------------------------------------------
// FALLBACK (round-1): reg-staged with in-flight f32->bf16 conversion.
// ---------------------------------------------------------------------------
template<bool A_BF16, bool GELU_BF16_OUT>
__global__ __launch_bounds__(256, 2)
void gemm_nt(const void* __restrict__ Av, const float* __restrict__ B,
             void* __restrict__ Cv, int Mpe, int N, int K,
             int mtpe, int ntpe) {
    __shared__ u16 As[128 * 64];
    __shared__ u16 Bs[128 * 64];

    const int tid  = threadIdx.x;
    const int lane = tid & 63;
    const int w    = tid >> 6;
    const int wr   = w >> 1, wc = w & 1;
    const int lr   = lane & 15;
    const int lkb  = (lane >> 4) << 3;

    const int nwg = gridDim.x;
    const int cpx = nwg >> 3;
    const int bid = blockIdx.x;
    const int wg  = (bid & 7) * cpx + (bid >> 3);

    const int tpe = mtpe * ntpe;
    const int e   = wg / tpe;
    const int rem = wg - e * tpe;
    const int mt  = rem / ntpe;
    const int nt  = rem - mt * ntpe;

    const size_t Abase = (size_t)e * Mpe * K + (size_t)mt * 128 * K;
    const size_t Bbase = (size_t)e * N   * K + (size_t)nt * 128 * K;

    const int srow = tid >> 3;
    const int scol = (tid & 7) << 3;

    f32x4 acc[4][4] = {};

    const float* Af = (const float*)Av;
    const u16*   Ab = (const u16*)Av;

    for (int k0 = 0; k0 < K; k0 += 64) {
        #pragma unroll
        for (int p = 0; p < 4; ++p) {
            const int row = (p << 5) + srow;
            const int di  = (row << 6) + (scol ^ ((row & 7) << 3));
            if constexpr (A_BF16) {
                const u16* ap = Ab + Abase + (size_t)row * K + k0 + scol;
                *(uint4*)&As[di] = *(const uint4*)ap;
            } else {
                const float* ap = Af + Abase + (size_t)row * K + k0 + scol;
                float4 v0 = *(const float4*)ap;
                float4 v1 = *(const float4*)(ap + 4);
                uint4 pk;
                pk.x = cvt2(v0.x, v0.y); pk.y = cvt2(v0.z, v0.w);
                pk.z = cvt2(v1.x, v1.y); pk.w = cvt2(v1.z, v1.w);
                *(uint4*)&As[di] = pk;
            }
            {
                const float* bp = B + Bbase + (size_t)row * K + k0 + scol;
                float4 v0 = *(const float4*)bp;
                float4 v1 = *(const float4*)(bp + 4);
                uint4 pk;
                pk.x = cvt2(v0.x, v0.y); pk.y = cvt2(v0.z, v0.w);
                pk.z = cvt2(v1.x, v1.y); pk.w = cvt2(v1.z, v1.w);
                *(uint4*)&Bs[di] = pk;
            }
        }
        __syncthreads();

        #pragma unroll
        for (int ks = 0; ks < 2; ++ks) {
            const int kcol = (ks << 5) + lkb;
            bf16x8 af[4], bfv[4];
            #pragma unroll
            for (int m = 0; m < 4; ++m) {
                const int row = wr * 64 + m * 16 + lr;
                af[m] = *(const bf16x8*)&As[(row << 6) + (kcol ^ ((row & 7) << 3))];
            }
            #pragma unroll
            for (int n = 0; n < 4; ++n) {
                const int row = wc * 64 + n * 16 + lr;
                bfv[n] = *(const bf16x8*)&Bs[(row << 6) + (kcol ^ ((row & 7) << 3))];
            }
            #pragma unroll
            for (int m = 0; m < 4; ++m)
                #pragma unroll
                for (int n = 0; n < 4; ++n)
                    acc[m][n] = __builtin_amdgcn_mfma_f32_16x16x32_bf16(
                        af[m], bfv[n], acc[m][n], 0, 0, 0);
        }
        __syncthreads();
    }

    const int r0 = (lane >> 4) << 2;
    if constexpr (GELU_BF16_OUT) {
        u16* Cb = (u16*)Cv;
        #pragma unroll
        for (int m = 0; m < 4; ++m)
            #pragma unroll
            for (int n = 0; n < 4; ++n) {
                const int col = nt * 128 + wc * 64 + n * 16 + lr;
                #pragma unroll
                for (int j = 0; j < 4; ++j) {
                    const int row = mt * 128 + wr * 64 + m * 16 + r0 + j;
                    Cb[((size_t)e * Mpe + row) * N + col] =
                        f2bf(gelu_tanh(acc[m][n][j]));
                }
            }
    } else {
        float* Cf = (float*)Cv;
        #pragma unroll
        for (int m = 0; m < 4; ++m)
            #pragma unroll
            for (int n = 0; n < 4; ++n) {
                const int col = nt * 128 + wc * 64 + n * 16 + lr;
                #pragma unroll
                for (int j = 0; j < 4; ++j) {
                    const int row = mt * 128 + wr * 64 + m * 16 + r0 + j;
                    Cf[((size_t)e * Mpe + row) * N + col] = acc[m][n][j];
                }
            }
    }
}

extern "C" void kernel_launch(void* const* d_in, const int* in_sizes, int n_in,
                              void* d_out, int out_size, void* d_ws, size_t ws_size,
                              hipStream_t stream) {
    const float* x  = (const float*)d_in[0];   // (T, H)
    const float* w1 = (const float*)d_in[1];   // (E, F, H)
    const float* w2 = (const float*)d_in[2];   // (E, H, F)
    float* out = (float*)d_out;                // (T, H) f32

    const size_t A_WS_B = (size_t)T_TOK * F_DIM * 2;               // 134217728
    const size_t XB_B   = (size_t)T_TOK * H_DIM * 2;               //  67108864
    const size_t W_B    = (size_t)E_NUM * F_DIM * H_DIM * 2;       // 134217728
    const size_t NEED   = A_WS_B + XB_B + 2 * W_B;                 // 469762048

    u16* a_ws = (u16*)d_ws;
    dim3 blk(256);

    if (ws_size >= NEED) {
        u16* xb  = (u16*)((char*)d_ws + A_WS_B);
        u16* w1b = (u16*)((char*)d_ws + A_WS_B + XB_B);
        u16* w2b = (u16*)((char*)d_ws + A_WS_B + XB_B + W_B);

        cvt_f32_bf16<<<2048, blk, 0, stream>>>(x,  xb,  (long)T_TOK * H_DIM);
        cvt_f32_bf16<<<2048, blk, 0, stream>>>(w1, w1b, (long)E_NUM * F_DIM * H_DIM);
        cvt_f32_bf16<<<2048, blk, 0, stream>>>(w2, w2b, (long)E_NUM * H_DIM * F_DIM);

        // GEMM1: per expert M=2048, N=4096, K=2048 -> 8*8*16 = 1024 blocks
        const int grid1 = E_NUM * (CAPX / 256) * (F_DIM / 256);
        gemm8p<true><<<grid1, dim3(512), 0, stream>>>(
            xb, w1b, (void*)a_ws, CAPX, F_DIM, H_DIM, CAPX / 256, F_DIM / 256);

        // GEMM2: per expert M=2048, N=2048, K=4096 -> 8*8*8 = 512 blocks
        const int grid2 = E_NUM * (CAPX / 256) * (H_DIM / 256);
        gemm8p<false><<<grid2, dim3(512), 0, stream>>>(
            a_ws, w2b, (void*)out, CAPX, H_DIM, F_DIM, CAPX / 256, H_DIM / 256);
    } else {
        const int grid1 = E_NUM * (CAPX / 128) * (F_DIM / 128);
        gemm_nt<false, true><<<grid1, blk, 0, stream>>>(
            (const void*)x, w1, (void*)a_ws, CAPX, F_DIM, H_DIM,
            CAPX / 128, F_DIM / 128);

        const int grid2 = E_NUM * (CAPX / 128) * (H_DIM / 128);
        gemm_nt<true, false><<<grid2, blk, 0, stream>>>(
            (const void*)a_ws, w2, (void*)out, CAPX, H_DIM, F_DIM,
            CAPX / 128, H_DIM / 128);
    }
}

// Round 5
// 705.990 us; speedup vs baseline: 1.0045x; 1.0045x over previous
//
#include <hip/hip_runtime.h>
#include <hip/hip_bf16.h>

typedef unsigned short u16;
typedef __attribute__((ext_vector_type(8))) short bf16x8;
typedef __attribute__((ext_vector_type(4))) float f32x4;

#define T_TOK 16384
#define H_DIM 2048
#define F_DIM 4096
#define E_NUM 8
#define CAPX  2048   // tokens per expert

__device__ __forceinline__ unsigned cvt2(float a, float b) {
    __hip_bfloat162 h = __float22bfloat162_rn(make_float2(a, b));
    union { __hip_bfloat162 h; unsigned u; } c; c.h = h; return c.u;
}
__device__ __forceinline__ u16 f2bf(float f) {
    __hip_bfloat16 h = __float2bfloat16(f);
    union { __hip_bfloat16 h; u16 u; } c; c.h = h; return c.u;
}
__device__ __forceinline__ float gelu_tanh(float x) {
    float x3 = x * x * x;
    float z = 0.7978845608028654f * (x + 0.044715f * x3);
    float e = __expf(2.0f * z);
    float t = 1.0f - 2.0f / (e + 1.0f);   // tanh(z)
    return 0.5f * x * (1.0f + t);
}

__device__ __forceinline__ void gload_lds16(const void* g, void* l) {
    __builtin_amdgcn_global_load_lds(
        (const __attribute__((address_space(1))) void*)g,
        (__attribute__((address_space(3))) void*)l,
        16, 0, 0);
}

// ---------------------------------------------------------------------------
// f32 -> bf16 conversion pre-pass
// ---------------------------------------------------------------------------
__global__ void cvt_f32_bf16(const float* __restrict__ in, u16* __restrict__ out,
                             long n) {
    long i = (((long)blockIdx.x * blockDim.x) + threadIdx.x) << 3;
    const long stride = ((long)gridDim.x * blockDim.x) << 3;
    for (; i < n; i += stride) {
        float4 v0 = *(const float4*)(in + i);
        float4 v1 = *(const float4*)(in + i + 4);
        uint4 pk;
        pk.x = cvt2(v0.x, v0.y); pk.y = cvt2(v0.z, v0.w);
        pk.z = cvt2(v1.x, v1.y); pk.w = cvt2(v1.z, v1.w);
        *(uint4*)(out + i) = pk;
    }
}

// ---------------------------------------------------------------------------
// 256x256 8-phase bf16 NT GEMM, single-region phases (reads+stage+MFMA
// co-scheduled; compiler inserts fine-grained lgkmcnt), one barrier/phase.
// C[M,N] = A[M,K] @ B[N,K]^T per expert.
// 512 thr = 8 waves (2M x 4N); per-wave 128x64 out = acc[8][4] f32x4.
// BK=64 as 2 K-halves of 32; LDS = 2buf x (A 32K + B 32K) = 128 KiB.
// Stage rotation (iter = tiles t->buf0, t+1->buf1):
//   p1:A1(t+1)  p2:B0(t+2) p3:A0(t+2) p4:[vmcnt(4)] B1(t+2)
//   p5:A1(t+2)  p6:B0(t+3) p7:A0(t+3) p8:[vmcnt(4)] B1(t+3)
// vmcnt(4) at p4-start guarantees landing of loads issued >=3 phases back
// (incl. prev p6/p7/p8 and this iter's p1) before the reads that need them.
// Drain->stage spacing >= 2 regions for every slot (1 barrier between the
// reader's lgkmcnt drain and the overwriting stage issue) -> WAR-safe.
// Swizzle: 16B-slot' = slot ^ ((row>>1)&3), both sides (rule 21).
// ---------------------------------------------------------------------------
template<bool GELU_BF16_OUT>
__global__ __launch_bounds__(512, 2)
void gemm8p(const u16* __restrict__ A, const u16* __restrict__ B,
            void* __restrict__ Cv, int Mpe, int N, int K,
            int mtpe, int ntpe) {
    __shared__ uint4 lds4[8192];          // 128 KiB
    char* ldsb = (char*)lds4;

    const int tid  = threadIdx.x;
    const int lane = tid & 63;
    const int wid  = tid >> 6;
    const int wm   = wid >> 2;            // 0..1
    const int wn   = wid & 3;             // 0..3
    const int lr   = lane & 15;

    // XCD-aware bijective swizzle (grid % 8 == 0)
    const int nwg = gridDim.x;
    const int cpx = nwg >> 3;
    const int bid = blockIdx.x;
    const int wg  = (bid & 7) * cpx + (bid >> 3);

    const int tpe = mtpe * ntpe;
    const int e   = wg / tpe;
    const int rem = wg - e * tpe;
    const int mt  = rem / ntpe;
    const int nt  = rem - mt * ntpe;

    const u16* Abase = A + (size_t)e * Mpe * K + (size_t)mt * 256 * K;
    const u16* Bbase = B + (size_t)e * N   * K + (size_t)nt * 256 * K;

    // staging pointers (bytes); row = tid>>2 (+128), pre-swizzled source slot
    const int srow = tid >> 2;
    const int sx   = (tid & 3) ^ ((tid >> 3) & 3);
    const char* pA0 = (const char*)(Abase + (size_t)srow * K + sx * 8);
    const char* pA1 = (const char*)(Abase + (size_t)(srow + 128) * K + sx * 8);
    const char* pB0 = (const char*)(Bbase + (size_t)srow * K + sx * 8);
    const char* pB1 = (const char*)(Bbase + (size_t)(srow + 128) * K + sx * 8);
    char* ldsw = ldsb + (wid << 10);

    // read-side per-thread byte offsets (swizzled slot)
    const int slotp = (((lane >> 4) ^ ((lr >> 1) & 3)) << 4);
    const int aoffb = ((wm * 128 + lr) << 6) + slotp;
    const int boffb = ((wn * 64  + lr) << 6) + slotp;

    const int NT = K >> 6;   // K-tiles (even)

    f32x4 acc[8][4] = {};
    bf16x8 afA[4], afB[4], bfA[4], bfB[4];

#define STAGE_A(KH, BUF, DOFF) do {                                           \
    char* d_ = ldsw + (BUF) * 32768 + (KH) * 16384;                           \
    gload_lds16(pA0 + (DOFF) + (KH) * 64, d_);                                \
    gload_lds16(pA1 + (DOFF) + (KH) * 64, d_ + 8192);                         \
} while (0)

#define STAGE_B(KH, BUF, DOFF) do {                                           \
    char* d_ = ldsw + 65536 + (BUF) * 32768 + (KH) * 16384;                   \
    gload_lds16(pB0 + (DOFF) + (KH) * 64, d_);                                \
    gload_lds16(pB1 + (DOFF) + (KH) * 64, d_ + 8192);                         \
} while (0)

#define READ_A(DST, BUF, KS, MH) do {                                         \
    const char* ab_ = ldsb + (BUF) * 32768 + (KS) * 16384 + (MH) * 4096 + aoffb; \
    DST[0] = *(const bf16x8*)(ab_);                                           \
    DST[1] = *(const bf16x8*)(ab_ + 1024);                                    \
    DST[2] = *(const bf16x8*)(ab_ + 2048);                                    \
    DST[3] = *(const bf16x8*)(ab_ + 3072);                                    \
} while (0)

#define READ_B(DST, BUF, KS) do {                                             \
    const char* bb_ = ldsb + 65536 + (BUF) * 32768 + (KS) * 16384 + boffb;    \
    DST[0] = *(const bf16x8*)(bb_);                                           \
    DST[1] = *(const bf16x8*)(bb_ + 1024);                                    \
    DST[2] = *(const bf16x8*)(bb_ + 2048);                                    \
    DST[3] = *(const bf16x8*)(bb_ + 3072);                                    \
} while (0)

// one barrier per phase; region interior is freely schedulable
#define BARX() do { __builtin_amdgcn_sched_barrier(0);                        \
                    __builtin_amdgcn_s_barrier();                             \
                    __builtin_amdgcn_sched_barrier(0); } while (0)
#define VM4()  asm volatile("s_waitcnt vmcnt(4)" ::: "memory")

#define MFMA16(AF, BF, MH) do {                                               \
    __builtin_amdgcn_s_setprio(1);                                            \
    _Pragma("unroll")                                                         \
    for (int i_ = 0; i_ < 4; ++i_) {                                          \
        _Pragma("unroll")                                                     \
        for (int n_ = 0; n_ < 4; ++n_)                                        \
            acc[(MH)*4 + i_][n_] = __builtin_amdgcn_mfma_f32_16x16x32_bf16(   \
                AF[i_], BF[n_], acc[(MH)*4 + i_][n_], 0, 0, 0);               \
    }                                                                         \
    __builtin_amdgcn_s_setprio(0);                                            \
} while (0)

// Phase p region: stage + lookahead reads (operands of p+1) + MFMA(p).
#define ITER(D1, D2, D3) do {                                                  \
    /*p1*/ STAGE_A(1,1,(D1)); READ_A(afB,0,0,1);                               \
           MFMA16(afA,bfA,0); BARX();                                          \
    /*p2*/ STAGE_B(0,0,(D2)); READ_A(afA,0,1,0); READ_B(bfB,0,1);              \
           MFMA16(afB,bfA,1); BARX();                                          \
    /*p3*/ STAGE_A(0,0,(D2)); READ_A(afB,0,1,1);                               \
           MFMA16(afA,bfB,0); BARX();                                          \
    /*p4*/ VM4();                                                              \
           STAGE_B(1,0,(D2)); READ_A(afA,1,0,0); READ_B(bfA,1,0);              \
           MFMA16(afB,bfB,1); BARX();                                          \
    /*p5*/ STAGE_A(1,0,(D2)); READ_A(afB,1,0,1);                               \
           MFMA16(afA,bfA,0); BARX();                                          \
    /*p6*/ STAGE_B(0,1,(D3)); READ_A(afA,1,1,0); READ_B(bfB,1,1);              \
           MFMA16(afB,bfA,1); BARX();                                          \
    /*p7*/ STAGE_A(0,1,(D3)); READ_A(afB,1,1,1);                               \
           MFMA16(afA,bfB,0); BARX();                                          \
    /*p8*/ VM4();                                                              \
           STAGE_B(1,1,(D3)); READ_A(afA,0,0,0); READ_B(bfA,0,0);              \
           MFMA16(afB,bfB,1); BARX();                                          \
} while (0)

    // prologue: 7 half-tiles; full drain once, then initial reads
    STAGE_B(0, 0, 0);
    STAGE_A(0, 0, 0);
    STAGE_B(1, 0, 0);
    STAGE_A(1, 0, 0);
    STAGE_B(0, 1, 128);
    STAGE_A(0, 1, 128);
    STAGE_B(1, 1, 128);
    asm volatile("s_waitcnt vmcnt(0)" ::: "memory");
    __builtin_amdgcn_s_barrier();
    __builtin_amdgcn_sched_barrier(0);
    READ_A(afA, 0, 0, 0);
    READ_B(bfA, 0, 0);

    const int nmain = (NT >> 1) - 1;
    for (int it = 0; it < nmain; ++it) {
        ITER(128, 256, 384);
        pA0 += 256; pA1 += 256; pB0 += 256; pB1 += 256;
    }
    // peeled last iteration: p1's stage (t+1) still real; t+2/t+3 stages are
    // dead -> clamp to delta 0 (valid addresses, slots never consumed).
    ITER(128, 0, 0);

#undef STAGE_A
#undef STAGE_B
#undef READ_A
#undef READ_B
#undef BARX
#undef VM4
#undef MFMA16
#undef ITER

    // epilogue: C/D layout col = lane&15, row = (lane>>4)*4 + reg
    const int r0 = (lane >> 4) << 2;
    if constexpr (GELU_BF16_OUT) {
        u16* Cb = (u16*)Cv;
        #pragma unroll
        for (int m = 0; m < 8; ++m)
            #pragma unroll
            for (int n = 0; n < 4; ++n) {
                const int col = nt * 256 + wn * 64 + n * 16 + lr;
                #pragma unroll
                for (int j = 0; j < 4; ++j) {
                    const int row = mt * 256 + wm * 128 + m * 16 + r0 + j;
                    Cb[((size_t)e * Mpe + row) * N + col] =
                        f2bf(gelu_tanh(acc[m][n][j]));
                }
            }
    } else {
        float* Cf = (float*)Cv;
        #pragma unroll
        for (int m = 0; m < 8; ++m)
            #pragma unroll
            for (int n = 0; n < 4; ++n) {
                const int col = nt * 256 + wn * 64 + n * 16 + lr;
                #pragma unroll
                for (int j = 0; j < 4; ++j) {
                    const int row = mt * 256 + wm * 128 + m * 16 + r0 + j;
                    Cf[((size_t)e * Mpe + row) * N + col] = acc[m][n][j];
                }
            }
    }
}

// ---------------------------------------------------------------------------
// FALLBACK (round-1): reg-staged with in-flight f32->bf16 conversion.
// ---------------------------------------------------------------------------
template<bool A_BF16, bool GELU_BF16_OUT>
__global__ __launch_bounds__(256, 2)
void gemm_nt(const void* __restrict__ Av, const float* __restrict__ B,
             void* __restrict__ Cv, int Mpe, int N, int K,
             int mtpe, int ntpe) {
    __shared__ u16 As[128 * 64];
    __shared__ u16 Bs[128 * 64];

    const int tid  = threadIdx.x;
    const int lane = tid & 63;
    const int w    = tid >> 6;
    const int wr   = w >> 1, wc = w & 1;
    const int lr   = lane & 15;
    const int lkb  = (lane >> 4) << 3;

    const int nwg = gridDim.x;
    const int cpx = nwg >> 3;
    const int bid = blockIdx.x;
    const int wg  = (bid & 7) * cpx + (bid >> 3);

    const int tpe = mtpe * ntpe;
    const int e   = wg / tpe;
    const int rem = wg - e * tpe;
    const int mt  = rem / ntpe;
    const int nt  = rem - mt * ntpe;

    const size_t Abase = (size_t)e * Mpe * K + (size_t)mt * 128 * K;
    const size_t Bbase = (size_t)e * N   * K + (size_t)nt * 128 * K;

    const int srow = tid >> 3;
    const int scol = (tid & 7) << 3;

    f32x4 acc[4][4] = {};

    const float* Af = (const float*)Av;
    const u16*   Ab = (const u16*)Av;

    for (int k0 = 0; k0 < K; k0 += 64) {
        #pragma unroll
        for (int p = 0; p < 4; ++p) {
            const int row = (p << 5) + srow;
            const int di  = (row << 6) + (scol ^ ((row & 7) << 3));
            if constexpr (A_BF16) {
                const u16* ap = Ab + Abase + (size_t)row * K + k0 + scol;
                *(uint4*)&As[di] = *(const uint4*)ap;
            } else {
                const float* ap = Af + Abase + (size_t)row * K + k0 + scol;
                float4 v0 = *(const float4*)ap;
                float4 v1 = *(const float4*)(ap + 4);
                uint4 pk;
                pk.x = cvt2(v0.x, v0.y); pk.y = cvt2(v0.z, v0.w);
                pk.z = cvt2(v1.x, v1.y); pk.w = cvt2(v1.z, v1.w);
                *(uint4*)&As[di] = pk;
            }
            {
                const float* bp = B + Bbase + (size_t)row * K + k0 + scol;
                float4 v0 = *(const float4*)bp;
                float4 v1 = *(const float4*)(bp + 4);
                uint4 pk;
                pk.x = cvt2(v0.x, v0.y); pk.y = cvt2(v0.z, v0.w);
                pk.z = cvt2(v1.x, v1.y); pk.w = cvt2(v1.z, v1.w);
                *(uint4*)&Bs[di] = pk;
            }
        }
        __syncthreads();

        #pragma unroll
        for (int ks = 0; ks < 2; ++ks) {
            const int kcol = (ks << 5) + lkb;
            bf16x8 af[4], bfv[4];
            #pragma unroll
            for (int m = 0; m < 4; ++m) {
                const int row = wr * 64 + m * 16 + lr;
                af[m] = *(const bf16x8*)&As[(row << 6) + (kcol ^ ((row & 7) << 3))];
            }
            #pragma unroll
            for (int n = 0; n < 4; ++n) {
                const int row = wc * 64 + n * 16 + lr;
                bfv[n] = *(const bf16x8*)&Bs[(row << 6) + (kcol ^ ((row & 7) << 3))];
            }
            #pragma unroll
            for (int m = 0; m < 4; ++m)
                #pragma unroll
                for (int n = 0; n < 4; ++n)
                    acc[m][n] = __builtin_amdgcn_mfma_f32_16x16x32_bf16(
                        af[m], bfv[n], acc[m][n], 0, 0, 0);
        }
        __syncthreads();
    }

    const int r0 = (lane >> 4) << 2;
    if constexpr (GELU_BF16_OUT) {
        u16* Cb = (u16*)Cv;
        #pragma unroll
        for (int m = 0; m < 4; ++m)
            #pragma unroll
            for (int n = 0; n < 4; ++n) {
                const int col = nt * 128 + wc * 64 + n * 16 + lr;
                #pragma unroll
                for (int j = 0; j < 4; ++j) {
                    const int row = mt * 128 + wr * 64 + m * 16 + r0 + j;
                    Cb[((size_t)e * Mpe + row) * N + col] =
                        f2bf(gelu_tanh(acc[m][n][j]));
                }
            }
    } else {
        float* Cf = (float*)Cv;
        #pragma unroll
        for (int m = 0; m < 4; ++m)
            #pragma unroll
            for (int n = 0; n < 4; ++n) {
                const int col = nt * 128 + wc * 64 + n * 16 + lr;
                #pragma unroll
                for (int j = 0; j < 4; ++j) {
                    const int row = mt * 128 + wr * 64 + m * 16 + r0 + j;
                    Cf[((size_t)e * Mpe + row) * N + col] = acc[m][n][j];
                }
            }
    }
}

extern "C" void kernel_launch(void* const* d_in, const int* in_sizes, int n_in,
                              void* d_out, int out_size, void* d_ws, size_t ws_size,
                              hipStream_t stream) {
    const float* x  = (const float*)d_in[0];   // (T, H)
    const float* w1 = (const float*)d_in[1];   // (E, F, H)
    const float* w2 = (const float*)d_in[2];   // (E, H, F)
    float* out = (float*)d_out;                // (T, H) f32

    const size_t A_WS_B = (size_t)T_TOK * F_DIM * 2;               // 134217728
    const size_t XB_B   = (size_t)T_TOK * H_DIM * 2;               //  67108864
    const size_t W_B    = (size_t)E_NUM * F_DIM * H_DIM * 2;       // 134217728
    const size_t NEED   = A_WS_B + XB_B + 2 * W_B;                 // 469762048

    u16* a_ws = (u16*)d_ws;
    dim3 blk(256);

    if (ws_size >= NEED) {
        u16* xb  = (u16*)((char*)d_ws + A_WS_B);
        u16* w1b = (u16*)((char*)d_ws + A_WS_B + XB_B);
        u16* w2b = (u16*)((char*)d_ws + A_WS_B + XB_B + W_B);

        cvt_f32_bf16<<<2048, blk, 0, stream>>>(x,  xb,  (long)T_TOK * H_DIM);
        cvt_f32_bf16<<<2048, blk, 0, stream>>>(w1, w1b, (long)E_NUM * F_DIM * H_DIM);
        cvt_f32_bf16<<<2048, blk, 0, stream>>>(w2, w2b, (long)E_NUM * H_DIM * F_DIM);

        // GEMM1: per expert M=2048, N=4096, K=2048 -> 8*8*16 = 1024 blocks
        const int grid1 = E_NUM * (CAPX / 256) * (F_DIM / 256);
        gemm8p<true><<<grid1, dim3(512), 0, stream>>>(
            xb, w1b, (void*)a_ws, CAPX, F_DIM, H_DIM, CAPX / 256, F_DIM / 256);

        // GEMM2: per expert M=2048, N=2048, K=4096 -> 8*8*8 = 512 blocks
        const int grid2 = E_NUM * (CAPX / 256) * (H_DIM / 256);
        gemm8p<false><<<grid2, dim3(512), 0, stream>>>(
            a_ws, w2b, (void*)out, CAPX, H_DIM, F_DIM, CAPX / 256, H_DIM / 256);
    } else {
        const int grid1 = E_NUM * (CAPX / 128) * (F_DIM / 128);
        gemm_nt<false, true><<<grid1, blk, 0, stream>>>(
            (const void*)x, w1, (void*)a_ws, CAPX, F_DIM, H_DIM,
            CAPX / 128, F_DIM / 128);

        const int grid2 = E_NUM * (CAPX / 128) * (H_DIM / 128);
        gemm_nt<true, false><<<grid2, blk, 0, stream>>>(
            (const void*)a_ws, w2, (void*)out, CAPX, H_DIM, F_DIM,
            CAPX / 128, H_DIM / 128);
    }
}

// Round 6
// 693.306 us; speedup vs baseline: 1.0229x; 1.0183x over previous
//
#include <hip/hip_runtime.h>
#include <hip/hip_bf16.h>

typedef unsigned short u16;
typedef __attribute__((ext_vector_type(8))) short bf16x8;
typedef __attribute__((ext_vector_type(4))) float f32x4;

#define T_TOK 16384
#define H_DIM 2048
#define F_DIM 4096
#define E_NUM 8
#define CAPX  2048   // tokens per expert

__device__ __forceinline__ unsigned cvt2(float a, float b) {
    __hip_bfloat162 h = __float22bfloat162_rn(make_float2(a, b));
    union { __hip_bfloat162 h; unsigned u; } c; c.h = h; return c.u;
}
__device__ __forceinline__ u16 f2bf(float f) {
    __hip_bfloat16 h = __float2bfloat16(f);
    union { __hip_bfloat16 h; u16 u; } c; c.h = h; return c.u;
}
__device__ __forceinline__ float gelu_tanh(float x) {
    float x3 = x * x * x;
    float z = 0.7978845608028654f * (x + 0.044715f * x3);
    float e = __expf(2.0f * z);
    float t = 1.0f - 2.0f / (e + 1.0f);   // tanh(z)
    return 0.5f * x * (1.0f + t);
}

__device__ __forceinline__ void gload_lds16(const void* g, void* l) {
    __builtin_amdgcn_global_load_lds(
        (const __attribute__((address_space(1))) void*)g,
        (__attribute__((address_space(3))) void*)l,
        16, 0, 0);
}

// ---------------------------------------------------------------------------
// f32 -> bf16 conversion pre-pass
// ---------------------------------------------------------------------------
__global__ void cvt_f32_bf16(const float* __restrict__ in, u16* __restrict__ out,
                             long n) {
    long i = (((long)blockIdx.x * blockDim.x) + threadIdx.x) << 3;
    const long stride = ((long)gridDim.x * blockDim.x) << 3;
    for (; i < n; i += stride) {
        float4 v0 = *(const float4*)(in + i);
        float4 v1 = *(const float4*)(in + i + 4);
        uint4 pk;
        pk.x = cvt2(v0.x, v0.y); pk.y = cvt2(v0.z, v0.w);
        pk.z = cvt2(v1.x, v1.y); pk.w = cvt2(v1.z, v1.w);
        *(uint4*)(out + i) = pk;
    }
}

// ---------------------------------------------------------------------------
// 256x256 8-phase bf16 NT GEMM (same schedule as round-5) + L2-aware
// super-tile rasterization: within each XCD's contiguous wg chunk, tiles are
// ordered in 4mt x 8nt super-tiles (= the 32-block concurrent set per XCD),
// serpentine across super-tiles so consecutive super-tiles share A panels.
// Shrinks the per-XCD live panel working set (GEMM1: 18 MB -> 12 MB).
// ---------------------------------------------------------------------------
template<bool GELU_BF16_OUT>
__global__ __launch_bounds__(512, 2)
void gemm8p(const u16* __restrict__ A, const u16* __restrict__ B,
            void* __restrict__ Cv, int Mpe, int N, int K,
            int mtpe, int ntpe) {
    __shared__ uint4 lds4[8192];          // 128 KiB
    char* ldsb = (char*)lds4;

    const int tid  = threadIdx.x;
    const int lane = tid & 63;
    const int wid  = tid >> 6;
    const int wm   = wid >> 2;            // 0..1
    const int wn   = wid & 3;             // 0..3
    const int lr   = lane & 15;

    // XCD-aware bijective swizzle (grid % 8 == 0)
    const int nwg = gridDim.x;
    const int cpx = nwg >> 3;
    const int bid = blockIdx.x;
    const int wg  = (bid & 7) * cpx + (bid >> 3);

    const int tpe = mtpe * ntpe;
    const int e   = wg / tpe;
    const int s   = wg - e * tpe;

    // super-tile raster: 32 tiles per super-tile (4 mt x 8 nt), serpentine
    int mt, nt;
    if ((mtpe & 3) == 0 && (ntpe & 7) == 0) {
        const int nsc   = ntpe >> 3;          // super-cols
        const int stile = s >> 5;
        const int w     = s & 31;
        const int str_  = stile / nsc;
        int       stc_  = stile - str_ * nsc;
        if (str_ & 1) stc_ = nsc - 1 - stc_;  // serpentine for A-panel reuse
        mt = str_ * 4 + (w & 3);
        nt = stc_ * 8 + (w >> 2);
    } else {
        mt = s / ntpe;
        nt = s - mt * ntpe;
    }

    const u16* Abase = A + (size_t)e * Mpe * K + (size_t)mt * 256 * K;
    const u16* Bbase = B + (size_t)e * N   * K + (size_t)nt * 256 * K;

    // staging pointers (bytes); row = tid>>2 (+128), pre-swizzled source slot
    const int srow = tid >> 2;
    const int sx   = (tid & 3) ^ ((tid >> 3) & 3);
    const char* pA0 = (const char*)(Abase + (size_t)srow * K + sx * 8);
    const char* pA1 = (const char*)(Abase + (size_t)(srow + 128) * K + sx * 8);
    const char* pB0 = (const char*)(Bbase + (size_t)srow * K + sx * 8);
    const char* pB1 = (const char*)(Bbase + (size_t)(srow + 128) * K + sx * 8);
    char* ldsw = ldsb + (wid << 10);

    // read-side per-thread byte offsets (swizzled slot)
    const int slotp = (((lane >> 4) ^ ((lr >> 1) & 3)) << 4);
    const int aoffb = ((wm * 128 + lr) << 6) + slotp;
    const int boffb = ((wn * 64  + lr) << 6) + slotp;

    const int NT = K >> 6;   // K-tiles (even)

    f32x4 acc[8][4] = {};
    bf16x8 afA[4], afB[4], bfA[4], bfB[4];

#define STAGE_A(KH, BUF, DOFF) do {                                           \
    char* d_ = ldsw + (BUF) * 32768 + (KH) * 16384;                           \
    gload_lds16(pA0 + (DOFF) + (KH) * 64, d_);                                \
    gload_lds16(pA1 + (DOFF) + (KH) * 64, d_ + 8192);                         \
} while (0)

#define STAGE_B(KH, BUF, DOFF) do {                                           \
    char* d_ = ldsw + 65536 + (BUF) * 32768 + (KH) * 16384;                   \
    gload_lds16(pB0 + (DOFF) + (KH) * 64, d_);                                \
    gload_lds16(pB1 + (DOFF) + (KH) * 64, d_ + 8192);                         \
} while (0)

#define READ_A(DST, BUF, KS, MH) do {                                         \
    const char* ab_ = ldsb + (BUF) * 32768 + (KS) * 16384 + (MH) * 4096 + aoffb; \
    DST[0] = *(const bf16x8*)(ab_);                                           \
    DST[1] = *(const bf16x8*)(ab_ + 1024);                                    \
    DST[2] = *(const bf16x8*)(ab_ + 2048);                                    \
    DST[3] = *(const bf16x8*)(ab_ + 3072);                                    \
} while (0)

#define READ_B(DST, BUF, KS) do {                                             \
    const char* bb_ = ldsb + 65536 + (BUF) * 32768 + (KS) * 16384 + boffb;    \
    DST[0] = *(const bf16x8*)(bb_);                                           \
    DST[1] = *(const bf16x8*)(bb_ + 1024);                                    \
    DST[2] = *(const bf16x8*)(bb_ + 2048);                                    \
    DST[3] = *(const bf16x8*)(bb_ + 3072);                                    \
} while (0)

// one barrier per phase; region interior is freely schedulable
#define BARX() do { __builtin_amdgcn_sched_barrier(0);                        \
                    __builtin_amdgcn_s_barrier();                             \
                    __builtin_amdgcn_sched_barrier(0); } while (0)
#define VM4()  asm volatile("s_waitcnt vmcnt(4)" ::: "memory")

#define MFMA16(AF, BF, MH) do {                                               \
    __builtin_amdgcn_s_setprio(1);                                            \
    _Pragma("unroll")                                                         \
    for (int i_ = 0; i_ < 4; ++i_) {                                          \
        _Pragma("unroll")                                                     \
        for (int n_ = 0; n_ < 4; ++n_)                                        \
            acc[(MH)*4 + i_][n_] = __builtin_amdgcn_mfma_f32_16x16x32_bf16(   \
                AF[i_], BF[n_], acc[(MH)*4 + i_][n_], 0, 0, 0);               \
    }                                                                         \
    __builtin_amdgcn_s_setprio(0);                                            \
} while (0)

// Phase p region: stage + lookahead reads (operands of p+1) + MFMA(p).
#define ITER(D1, D2, D3) do {                                                  \
    /*p1*/ STAGE_A(1,1,(D1)); READ_A(afB,0,0,1);                               \
           MFMA16(afA,bfA,0); BARX();                                          \
    /*p2*/ STAGE_B(0,0,(D2)); READ_A(afA,0,1,0); READ_B(bfB,0,1);              \
           MFMA16(afB,bfA,1); BARX();                                          \
    /*p3*/ STAGE_A(0,0,(D2)); READ_A(afB,0,1,1);                               \
           MFMA16(afA,bfB,0); BARX();                                          \
    /*p4*/ VM4();                                                              \
           STAGE_B(1,0,(D2)); READ_A(afA,1,0,0); READ_B(bfA,1,0);              \
           MFMA16(afB,bfB,1); BARX();                                          \
    /*p5*/ STAGE_A(1,0,(D2)); READ_A(afB,1,0,1);                               \
           MFMA16(afA,bfA,0); BARX();                                          \
    /*p6*/ STAGE_B(0,1,(D3)); READ_A(afA,1,1,0); READ_B(bfB,1,1);              \
           MFMA16(afB,bfA,1); BARX();                                          \
    /*p7*/ STAGE_A(0,1,(D3)); READ_A(afB,1,1,1);                               \
           MFMA16(afA,bfB,0); BARX();                                          \
    /*p8*/ VM4();                                                              \
           STAGE_B(1,1,(D3)); READ_A(afA,0,0,0); READ_B(bfA,0,0);              \
           MFMA16(afB,bfB,1); BARX();                                          \
} while (0)

    // prologue: 7 half-tiles; full drain once, then initial reads
    STAGE_B(0, 0, 0);
    STAGE_A(0, 0, 0);
    STAGE_B(1, 0, 0);
    STAGE_A(1, 0, 0);
    STAGE_B(0, 1, 128);
    STAGE_A(0, 1, 128);
    STAGE_B(1, 1, 128);
    asm volatile("s_waitcnt vmcnt(0)" ::: "memory");
    __builtin_amdgcn_s_barrier();
    __builtin_amdgcn_sched_barrier(0);
    READ_A(afA, 0, 0, 0);
    READ_B(bfA, 0, 0);

    const int nmain = (NT >> 1) - 1;
    for (int it = 0; it < nmain; ++it) {
        ITER(128, 256, 384);
        pA0 += 256; pA1 += 256; pB0 += 256; pB1 += 256;
    }
    // peeled last iteration: p1's stage (t+1) still real; t+2/t+3 stages are
    // dead -> clamp to delta 0 (valid addresses, slots never consumed).
    ITER(128, 0, 0);

#undef STAGE_A
#undef STAGE_B
#undef READ_A
#undef READ_B
#undef BARX
#undef VM4
#undef MFMA16
#undef ITER

    // epilogue: C/D layout col = lane&15, row = (lane>>4)*4 + reg
    const int r0 = (lane >> 4) << 2;
    if constexpr (GELU_BF16_OUT) {
        u16* Cb = (u16*)Cv;
        #pragma unroll
        for (int m = 0; m < 8; ++m)
            #pragma unroll
            for (int n = 0; n < 4; ++n) {
                const int col = nt * 256 + wn * 64 + n * 16 + lr;
                #pragma unroll
                for (int j = 0; j < 4; ++j) {
                    const int row = mt * 256 + wm * 128 + m * 16 + r0 + j;
                    Cb[((size_t)e * Mpe + row) * N + col] =
                        f2bf(gelu_tanh(acc[m][n][j]));
                }
            }
    } else {
        float* Cf = (float*)Cv;
        #pragma unroll
        for (int m = 0; m < 8; ++m)
            #pragma unroll
            for (int n = 0; n < 4; ++n) {
                const int col = nt * 256 + wn * 64 + n * 16 + lr;
                #pragma unroll
                for (int j = 0; j < 4; ++j) {
                    const int row = mt * 256 + wm * 128 + m * 16 + r0 + j;
                    Cf[((size_t)e * Mpe + row) * N + col] = acc[m][n][j];
                }
            }
    }
}

// ---------------------------------------------------------------------------
// FALLBACK (round-1): reg-staged with in-flight f32->bf16 conversion.
// ---------------------------------------------------------------------------
template<bool A_BF16, bool GELU_BF16_OUT>
__global__ __launch_bounds__(256, 2)
void gemm_nt(const void* __restrict__ Av, const float* __restrict__ B,
             void* __restrict__ Cv, int Mpe, int N, int K,
             int mtpe, int ntpe) {
    __shared__ u16 As[128 * 64];
    __shared__ u16 Bs[128 * 64];

    const int tid  = threadIdx.x;
    const int lane = tid & 63;
    const int w    = tid >> 6;
    const int wr   = w >> 1, wc = w & 1;
    const int lr   = lane & 15;
    const int lkb  = (lane >> 4) << 3;

    const int nwg = gridDim.x;
    const int cpx = nwg >> 3;
    const int bid = blockIdx.x;
    const int wg  = (bid & 7) * cpx + (bid >> 3);

    const int tpe = mtpe * ntpe;
    const int e   = wg / tpe;
    const int rem = wg - e * tpe;
    const int mt  = rem / ntpe;
    const int nt  = rem - mt * ntpe;

    const size_t Abase = (size_t)e * Mpe * K + (size_t)mt * 128 * K;
    const size_t Bbase = (size_t)e * N   * K + (size_t)nt * 128 * K;

    const int srow = tid >> 3;
    const int scol = (tid & 7) << 3;

    f32x4 acc[4][4] = {};

    const float* Af = (const float*)Av;
    const u16*   Ab = (const u16*)Av;

    for (int k0 = 0; k0 < K; k0 += 64) {
        #pragma unroll
        for (int p = 0; p < 4; ++p) {
            const int row = (p << 5) + srow;
            const int di  = (row << 6) + (scol ^ ((row & 7) << 3));
            if constexpr (A_BF16) {
                const u16* ap = Ab + Abase + (size_t)row * K + k0 + scol;
                *(uint4*)&As[di] = *(const uint4*)ap;
            } else {
                const float* ap = Af + Abase + (size_t)row * K + k0 + scol;
                float4 v0 = *(const float4*)ap;
                float4 v1 = *(const float4*)(ap + 4);
                uint4 pk;
                pk.x = cvt2(v0.x, v0.y); pk.y = cvt2(v0.z, v0.w);
                pk.z = cvt2(v1.x, v1.y); pk.w = cvt2(v1.z, v1.w);
                *(uint4*)&As[di] = pk;
            }
            {
                const float* bp = B + Bbase + (size_t)row * K + k0 + scol;
                float4 v0 = *(const float4*)bp;
                float4 v1 = *(const float4*)(bp + 4);
                uint4 pk;
                pk.x = cvt2(v0.x, v0.y); pk.y = cvt2(v0.z, v0.w);
                pk.z = cvt2(v1.x, v1.y); pk.w = cvt2(v1.z, v1.w);
                *(uint4*)&Bs[di] = pk;
            }
        }
        __syncthreads();

        #pragma unroll
        for (int ks = 0; ks < 2; ++ks) {
            const int kcol = (ks << 5) + lkb;
            bf16x8 af[4], bfv[4];
            #pragma unroll
            for (int m = 0; m < 4; ++m) {
                const int row = wr * 64 + m * 16 + lr;
                af[m] = *(const bf16x8*)&As[(row << 6) + (kcol ^ ((row & 7) << 3))];
            }
            #pragma unroll
            for (int n = 0; n < 4; ++n) {
                const int row = wc * 64 + n * 16 + lr;
                bfv[n] = *(const bf16x8*)&Bs[(row << 6) + (kcol ^ ((row & 7) << 3))];
            }
            #pragma unroll
            for (int m = 0; m < 4; ++m)
                #pragma unroll
                for (int n = 0; n < 4; ++n)
                    acc[m][n] = __builtin_amdgcn_mfma_f32_16x16x32_bf16(
                        af[m], bfv[n], acc[m][n], 0, 0, 0);
        }
        __syncthreads();
    }

    const int r0 = (lane >> 4) << 2;
    if constexpr (GELU_BF16_OUT) {
        u16* Cb = (u16*)Cv;
        #pragma unroll
        for (int m = 0; m < 4; ++m)
            #pragma unroll
            for (int n = 0; n < 4; ++n) {
                const int col = nt * 128 + wc * 64 + n * 16 + lr;
                #pragma unroll
                for (int j = 0; j < 4; ++j) {
                    const int row = mt * 128 + wr * 64 + m * 16 + r0 + j;
                    Cb[((size_t)e * Mpe + row) * N + col] =
                        f2bf(gelu_tanh(acc[m][n][j]));
                }
            }
    } else {
        float* Cf = (float*)Cv;
        #pragma unroll
        for (int m = 0; m < 4; ++m)
            #pragma unroll
            for (int n = 0; n < 4; ++n) {
                const int col = nt * 128 + wc * 64 + n * 16 + lr;
                #pragma unroll
                for (int j = 0; j < 4; ++j) {
                    const int row = mt * 128 + wr * 64 + m * 16 + r0 + j;
                    Cf[((size_t)e * Mpe + row) * N + col] = acc[m][n][j];
                }
            }
    }
}

extern "C" void kernel_launch(void* const* d_in, const int* in_sizes, int n_in,
                              void* d_out, int out_size, void* d_ws, size_t ws_size,
                              hipStream_t stream) {
    const float* x  = (const float*)d_in[0];   // (T, H)
    const float* w1 = (const float*)d_in[1];   // (E, F, H)
    const float* w2 = (const float*)d_in[2];   // (E, H, F)
    float* out = (float*)d_out;                // (T, H) f32

    const size_t A_WS_B = (size_t)T_TOK * F_DIM * 2;               // 134217728
    const size_t XB_B   = (size_t)T_TOK * H_DIM * 2;               //  67108864
    const size_t W_B    = (size_t)E_NUM * F_DIM * H_DIM * 2;       // 134217728
    const size_t NEED   = A_WS_B + XB_B + 2 * W_B;                 // 469762048

    u16* a_ws = (u16*)d_ws;
    dim3 blk(256);

    if (ws_size >= NEED) {
        u16* xb  = (u16*)((char*)d_ws + A_WS_B);
        u16* w1b = (u16*)((char*)d_ws + A_WS_B + XB_B);
        u16* w2b = (u16*)((char*)d_ws + A_WS_B + XB_B + W_B);

        cvt_f32_bf16<<<2048, blk, 0, stream>>>(x,  xb,  (long)T_TOK * H_DIM);
        cvt_f32_bf16<<<2048, blk, 0, stream>>>(w1, w1b, (long)E_NUM * F_DIM * H_DIM);
        cvt_f32_bf16<<<2048, blk, 0, stream>>>(w2, w2b, (long)E_NUM * H_DIM * F_DIM);

        // GEMM1: per expert M=2048, N=4096, K=2048 -> 8*8*16 = 1024 blocks
        const int grid1 = E_NUM * (CAPX / 256) * (F_DIM / 256);
        gemm8p<true><<<grid1, dim3(512), 0, stream>>>(
            xb, w1b, (void*)a_ws, CAPX, F_DIM, H_DIM, CAPX / 256, F_DIM / 256);

        // GEMM2: per expert M=2048, N=2048, K=4096 -> 8*8*8 = 512 blocks
        const int grid2 = E_NUM * (CAPX / 256) * (H_DIM / 256);
        gemm8p<false><<<grid2, dim3(512), 0, stream>>>(
            a_ws, w2b, (void*)out, CAPX, H_DIM, F_DIM, CAPX / 256, H_DIM / 256);
    } else {
        const int grid1 = E_NUM * (CAPX / 128) * (F_DIM / 128);
        gemm_nt<false, true><<<grid1, blk, 0, stream>>>(
            (const void*)x, w1, (void*)a_ws, CAPX, F_DIM, H_DIM,
            CAPX / 128, F_DIM / 128);

        const int grid2 = E_NUM * (CAPX / 128) * (H_DIM / 128);
        gemm_nt<true, false><<<grid2, blk, 0, stream>>>(
            (const void*)a_ws, w2, (void*)out, CAPX, H_DIM, F_DIM,
            CAPX / 128, H_DIM / 128);
    }
}

// Round 7
// 549.171 us; speedup vs baseline: 1.2914x; 1.2625x over previous
//
#include <hip/hip_runtime.h>
#include <hip/hip_bf16.h>

typedef unsigned short u16;
typedef unsigned char u8;
typedef __attribute__((ext_vector_type(8))) short bf16x8;
typedef __attribute__((ext_vector_type(4))) float f32x4;
typedef __attribute__((ext_vector_type(8))) int i32x8;
typedef __attribute__((ext_vector_type(16))) float f32x16;

#define T_TOK 16384
#define H_DIM 2048
#define F_DIM 4096
#define E_NUM 8
#define CAPX  2048   // tokens per expert

#define SCONE 0x7F7F7F7F   // e8m0 127 in every byte -> scale = 1.0

__device__ __forceinline__ unsigned cvt2(float a, float b) {
    __hip_bfloat162 h = __float22bfloat162_rn(make_float2(a, b));
    union { __hip_bfloat162 h; unsigned u; } c; c.h = h; return c.u;
}
__device__ __forceinline__ u16 f2bf(float f) {
    __hip_bfloat16 h = __float2bfloat16(f);
    union { __hip_bfloat16 h; u16 u; } c; c.h = h; return c.u;
}
__device__ __forceinline__ float gelu_tanh(float x) {
    float x3 = x * x * x;
    float z = 0.7978845608028654f * (x + 0.044715f * x3);
    float e = __expf(2.0f * z);
    float t = 1.0f - 2.0f / (e + 1.0f);   // tanh(z)
    return 0.5f * x * (1.0f + t);
}

__device__ __forceinline__ void gload_lds16(const void* g, void* l) {
    __builtin_amdgcn_global_load_lds(
        (const __attribute__((address_space(1))) void*)g,
        (__attribute__((address_space(3))) void*)l,
        16, 0, 0);
}

// ---------------------------------------------------------------------------
// f32 -> fp8 e4m3 conversion pre-pass with prescale (memory-bound)
// ---------------------------------------------------------------------------
__global__ void cvt_f32_fp8(const float* __restrict__ in, u8* __restrict__ out,
                            long n, float s) {
    long i = (((long)blockIdx.x * blockDim.x) + threadIdx.x) << 3;
    const long stride = ((long)gridDim.x * blockDim.x) << 3;
    for (; i < n; i += stride) {
        float4 v0 = *(const float4*)(in + i);
        float4 v1 = *(const float4*)(in + i + 4);
        int d0 = __builtin_amdgcn_cvt_pk_fp8_f32(v0.x * s, v0.y * s, 0, false);
        d0     = __builtin_amdgcn_cvt_pk_fp8_f32(v0.z * s, v0.w * s, d0, true);
        int d1 = __builtin_amdgcn_cvt_pk_fp8_f32(v1.x * s, v1.y * s, 0, false);
        d1     = __builtin_amdgcn_cvt_pk_fp8_f32(v1.z * s, v1.w * s, d1, true);
        uint2 pk; pk.x = (unsigned)d0; pk.y = (unsigned)d1;
        *(uint2*)(out + i) = pk;
    }
}

// ---------------------------------------------------------------------------
// 256x256 MX-fp8 NT GEMM: C[M,N] = dequant(A[M,K] @ B[N,K]^T) per expert.
// mfma_scale_f32_32x32x64_f8f6f4 (e4m3 both ops, unity scales; data prescaled,
// compensated by oscale in the epilogue).
// 512 thr = 8 waves (2M x 4N); per-wave 128x64 out = acc[4][2] f32x16.
// BK=128 (one LDS tile = 256 rows x 128 B = 32 KB/op); LDS = 2 bufs = 128 KiB.
// 4 phases per ITER (2 tiles, K-advance 256); phase (tile, ks=K-half-64):
//   p1: [vmcnt(0); BAR] stage {A1h0,B1h0}(t+1)    compute buf0 ks0
//   p2:               stage {A1h1,B1h1}(t+1)      compute buf0 ks1
//   p3: [vmcnt(0); BAR] stage {A0h0,B0h0}(t+2)    compute buf1 ks0
//   p4:               stage {A0h1,B0h1}(t+2)      compute buf1 ks1
// WAR: stages issue AFTER the barrier separating them from the old content's
// last readers (p1-bar covers p4-prev reads; p3-bar covers p2 reads).
// RAW: vmcnt(0) pre-barrier drains every wave's stages of the tile about to
// be read; barrier publishes. Only 2 barriers + 2 drains per K=256.
// Swizzle: 16B-slot' = slot ^ (row&7) in 128-B rows (conflict-free per
// 16-lane quarter); linear LDS dest + pre-swizzled global source (rule 21).
// Frag layout (32x32x64 f8f6f4): A lane l: row=l&31, k=(l>>5)*32+i (32 B);
// B same with col; C/D: col=lane&31, row=(reg&3)+8*(reg>>2)+4*(lane>>5).
// ---------------------------------------------------------------------------
template<int KB, bool GELU_FP8_OUT>
__global__ __launch_bounds__(512, 1)
void gemm_f8(const u8* __restrict__ A, const u8* __restrict__ B,
             void* __restrict__ Cv, int Mpe, int N,
             int mtpe, int ntpe, float oscale) {
    __shared__ uint4 lds4[8192];          // 128 KiB: A [2][256][128] @0, B @65536
    char* ldsb = (char*)lds4;

    const int tid  = threadIdx.x;
    const int lane = tid & 63;
    const int wid  = tid >> 6;
    const int wm   = wid >> 2;            // 0..1
    const int wn   = wid & 3;             // 0..3
    const int l31  = lane & 31;
    const int xr   = lane & 7;            // row&7 for all frag rows
    const int g2   = (lane >> 5) << 1;    // k-group slot base: 0 or 2

    // XCD-aware bijective swizzle (grid % 8 == 0)
    const int nwg = gridDim.x;
    const int cpx = nwg >> 3;
    const int bid = blockIdx.x;
    const int wg  = (bid & 7) * cpx + (bid >> 3);

    const int tpe = mtpe * ntpe;
    const int e   = wg / tpe;
    const int s   = wg - e * tpe;

    // super-tile raster: 32 tiles per super-tile (4 mt x 8 nt), serpentine
    int mt, nt;
    if ((mtpe & 3) == 0 && (ntpe & 7) == 0) {
        const int nsc   = ntpe >> 3;
        const int stile = s >> 5;
        const int w     = s & 31;
        const int str_  = stile / nsc;
        int       stc_  = stile - str_ * nsc;
        if (str_ & 1) stc_ = nsc - 1 - stc_;
        mt = str_ * 4 + (w & 3);
        nt = stc_ * 8 + (w >> 2);
    } else {
        mt = s / ntpe;
        nt = s - mt * ntpe;
    }

    const u8* Abase = A + (size_t)e * Mpe * KB + (size_t)mt * 256 * KB;
    const u8* Bbase = B + (size_t)e * N   * KB + (size_t)nt * 256 * KB;

    // staging: per gload instr a wave writes rows (i*64 + wid*8 + lane>>3),
    // dest slot = lane&7; source slot pre-swizzled: sx = (lane&7)^(lane>>3)
    const int srow = (wid << 3) + (lane >> 3);       // 0..63
    const int sx   = (lane & 7) ^ (lane >> 3);
    const u8* pA = Abase + (size_t)srow * KB + sx * 16;
    const u8* pB = Bbase + (size_t)srow * KB + sx * 16;

    f32x16 acc[4][2] = {};

#define STG_A(BUF, H, KOFF) do {                                              \
    char* d_ = ldsb + (BUF) * 32768 + (H) * 16384 + (wid << 10);              \
    gload_lds16(pA + (size_t)((H) * 128) * KB + (KOFF), d_);                  \
    gload_lds16(pA + (size_t)((H) * 128 + 64) * KB + (KOFF), d_ + 8192);      \
} while (0)

#define STG_B(BUF, H, KOFF) do {                                              \
    char* d_ = ldsb + 65536 + (BUF) * 32768 + (H) * 16384 + (wid << 10);      \
    gload_lds16(pB + (size_t)((H) * 128) * KB + (KOFF), d_);                  \
    gload_lds16(pB + (size_t)((H) * 128 + 64) * KB + (KOFF), d_ + 8192);      \
} while (0)

    union U8v { uint4 q[2]; i32x8 v; };

#define LD_FRAG(DST, BASEOFF, ROW, KS) do {                                   \
    const char* r_ = ldsb + (BASEOFF) + ((ROW) << 7);                         \
    U8v u_;                                                                   \
    u_.q[0] = *(const uint4*)(r_ + ((((KS) * 4 + g2 + 0) ^ xr) << 4));        \
    u_.q[1] = *(const uint4*)(r_ + ((((KS) * 4 + g2 + 1) ^ xr) << 4));        \
    DST = u_.v;                                                               \
} while (0)

#define MF(AV, BV, M, NN)                                                     \
    acc[M][NN] = __builtin_amdgcn_mfma_scale_f32_32x32x64_f8f6f4(             \
        AV, BV, acc[M][NN], 0, 0, 0, SCONE, 0, SCONE)

#define PHASE(BUF, KS) do {                                                   \
    i32x8 av0, av1, av2, av3, bv0, bv1;                                       \
    LD_FRAG(av0, (BUF) * 32768, wm * 128 + 0 * 32 + l31, KS);                 \
    LD_FRAG(av1, (BUF) * 32768, wm * 128 + 1 * 32 + l31, KS);                 \
    LD_FRAG(av2, (BUF) * 32768, wm * 128 + 2 * 32 + l31, KS);                 \
    LD_FRAG(av3, (BUF) * 32768, wm * 128 + 3 * 32 + l31, KS);                 \
    LD_FRAG(bv0, 65536 + (BUF) * 32768, wn * 64 + 0 * 32 + l31, KS);          \
    LD_FRAG(bv1, 65536 + (BUF) * 32768, wn * 64 + 1 * 32 + l31, KS);          \
    __builtin_amdgcn_s_setprio(1);                                            \
    MF(av0, bv0, 0, 0); MF(av0, bv1, 0, 1);                                   \
    MF(av1, bv0, 1, 0); MF(av1, bv1, 1, 1);                                   \
    MF(av2, bv0, 2, 0); MF(av2, bv1, 2, 1);                                   \
    MF(av3, bv0, 3, 0); MF(av3, bv1, 3, 1);                                   \
    __builtin_amdgcn_s_setprio(0);                                            \
} while (0)

#define VM0()  asm volatile("s_waitcnt vmcnt(0)" ::: "memory")
#define BARX() do { __builtin_amdgcn_sched_barrier(0);                        \
                    __builtin_amdgcn_s_barrier();                             \
                    __builtin_amdgcn_sched_barrier(0); } while (0)

    // prologue: tile 0 -> buf0 (4 halves, 8 gloads), drain, publish
    STG_A(0, 0, 0); STG_B(0, 0, 0);
    STG_A(0, 1, 0); STG_B(0, 1, 0);
    VM0();
    BARX();

    const int NI = KB / 256;   // ITERs (2 tiles each); KB=2048->8, 4096->16
    int kb = 0;
    for (int it = 0; it < NI; ++it) {
        const int k1 = kb + 128;                        // tile 2i+1 (real)
        const int k2 = (it == NI - 1) ? kb : kb + 256;  // tile 2i+2 (clamped)
        // p1: buf0 ks0 | stage buf1 h0
        VM0();            // drains prev p3/p4 stages (buf0 tile) - prologue at it=0
        BARX();
        STG_A(1, 0, k1); STG_B(1, 0, k1);
        PHASE(0, 0);
        // p2: buf0 ks1 | stage buf1 h1
        STG_A(1, 1, k1); STG_B(1, 1, k1);
        PHASE(0, 1);
        // p3: buf1 ks0 | stage next buf0 h0
        VM0();            // drains p1/p2 stages (buf1 tile)
        BARX();
        STG_A(0, 0, k2); STG_B(0, 0, k2);
        PHASE(1, 0);
        // p4: buf1 ks1 | stage next buf0 h1
        STG_A(0, 1, k2); STG_B(0, 1, k2);
        PHASE(1, 1);
        kb += 256;
    }

#undef STG_A
#undef STG_B
#undef LD_FRAG
#undef MF
#undef PHASE
#undef VM0
#undef BARX

    // epilogue: C/D 32x32 layout: col=lane&31, row=(r&3)+8*(r>>2)+4*(lane>>5)
    const int rbase = (lane >> 5) << 2;
    if constexpr (GELU_FP8_OUT) {
        u8* Cb = (u8*)Cv;
        #pragma unroll
        for (int m = 0; m < 4; ++m)
            #pragma unroll
            for (int n = 0; n < 2; ++n) {
                const int col = nt * 256 + wn * 64 + n * 32 + l31;
                #pragma unroll
                for (int r = 0; r < 16; ++r) {
                    const int row = mt * 256 + wm * 128 + m * 32 +
                                    (r & 3) + ((r >> 2) << 3) + rbase;
                    float h = acc[m][n][r] * oscale;
                    float a = gelu_tanh(h) * 8192.f;   // activation prescale 2^13
                    int p = __builtin_amdgcn_cvt_pk_fp8_f32(a, a, 0, false);
                    Cb[((size_t)e * Mpe + row) * N + col] = (u8)(p & 0xff);
                }
            }
    } else {
        float* Cf = (float*)Cv;
        #pragma unroll
        for (int m = 0; m < 4; ++m)
            #pragma unroll
            for (int n = 0; n < 2; ++n) {
                const int col = nt * 256 + wn * 64 + n * 32 + l31;
                #pragma unroll
                for (int r = 0; r < 16; ++r) {
                    const int row = mt * 256 + wm * 128 + m * 32 +
                                    (r & 3) + ((r >> 2) << 3) + rbase;
                    Cf[((size_t)e * Mpe + row) * N + col] = acc[m][n][r] * oscale;
                }
            }
    }
}

// ---------------------------------------------------------------------------
// FALLBACK (round-1): bf16 reg-staged with in-flight f32->bf16 conversion.
// ---------------------------------------------------------------------------
template<bool A_BF16, bool GELU_BF16_OUT>
__global__ __launch_bounds__(256, 2)
void gemm_nt(const void* __restrict__ Av, const float* __restrict__ B,
             void* __restrict__ Cv, int Mpe, int N, int K,
             int mtpe, int ntpe) {
    __shared__ u16 As[128 * 64];
    __shared__ u16 Bs[128 * 64];

    const int tid  = threadIdx.x;
    const int lane = tid & 63;
    const int w    = tid >> 6;
    const int wr   = w >> 1, wc = w & 1;
    const int lr   = lane & 15;
    const int lkb  = (lane >> 4) << 3;

    const int nwg = gridDim.x;
    const int cpx = nwg >> 3;
    const int bid = blockIdx.x;
    const int wg  = (bid & 7) * cpx + (bid >> 3);

    const int tpe = mtpe * ntpe;
    const int e   = wg / tpe;
    const int rem = wg - e * tpe;
    const int mt  = rem / ntpe;
    const int nt  = rem - mt * ntpe;

    const size_t Abase = (size_t)e * Mpe * K + (size_t)mt * 128 * K;
    const size_t Bbase = (size_t)e * N   * K + (size_t)nt * 128 * K;

    const int srow = tid >> 3;
    const int scol = (tid & 7) << 3;

    f32x4 acc[4][4] = {};

    const float* Af = (const float*)Av;
    const u16*   Ab = (const u16*)Av;

    for (int k0 = 0; k0 < K; k0 += 64) {
        #pragma unroll
        for (int p = 0; p < 4; ++p) {
            const int row = (p << 5) + srow;
            const int di  = (row << 6) + (scol ^ ((row & 7) << 3));
            if constexpr (A_BF16) {
                const u16* ap = Ab + Abase + (size_t)row * K + k0 + scol;
                *(uint4*)&As[di] = *(const uint4*)ap;
            } else {
                const float* ap = Af + Abase + (size_t)row * K + k0 + scol;
                float4 v0 = *(const float4*)ap;
                float4 v1 = *(const float4*)(ap + 4);
                uint4 pk;
                pk.x = cvt2(v0.x, v0.y); pk.y = cvt2(v0.z, v0.w);
                pk.z = cvt2(v1.x, v1.y); pk.w = cvt2(v1.z, v1.w);
                *(uint4*)&As[di] = pk;
            }
            {
                const float* bp = B + Bbase + (size_t)row * K + k0 + scol;
                float4 v0 = *(const float4*)bp;
                float4 v1 = *(const float4*)(bp + 4);
                uint4 pk;
                pk.x = cvt2(v0.x, v0.y); pk.y = cvt2(v0.z, v0.w);
                pk.z = cvt2(v1.x, v1.y); pk.w = cvt2(v1.z, v1.w);
                *(uint4*)&Bs[di] = pk;
            }
        }
        __syncthreads();

        #pragma unroll
        for (int ks = 0; ks < 2; ++ks) {
            const int kcol = (ks << 5) + lkb;
            bf16x8 af[4], bfv[4];
            #pragma unroll
            for (int m = 0; m < 4; ++m) {
                const int row = wr * 64 + m * 16 + lr;
                af[m] = *(const bf16x8*)&As[(row << 6) + (kcol ^ ((row & 7) << 3))];
            }
            #pragma unroll
            for (int n = 0; n < 4; ++n) {
                const int row = wc * 64 + n * 16 + lr;
                bfv[n] = *(const bf16x8*)&Bs[(row << 6) + (kcol ^ ((row & 7) << 3))];
            }
            #pragma unroll
            for (int m = 0; m < 4; ++m)
                #pragma unroll
                for (int n = 0; n < 4; ++n)
                    acc[m][n] = __builtin_amdgcn_mfma_f32_16x16x32_bf16(
                        af[m], bfv[n], acc[m][n], 0, 0, 0);
        }
        __syncthreads();
    }

    const int r0 = (lane >> 4) << 2;
    if constexpr (GELU_BF16_OUT) {
        u16* Cb = (u16*)Cv;
        #pragma unroll
        for (int m = 0; m < 4; ++m)
            #pragma unroll
            for (int n = 0; n < 4; ++n) {
                const int col = nt * 128 + wc * 64 + n * 16 + lr;
                #pragma unroll
                for (int j = 0; j < 4; ++j) {
                    const int row = mt * 128 + wr * 64 + m * 16 + r0 + j;
                    Cb[((size_t)e * Mpe + row) * N + col] =
                        f2bf(gelu_tanh(acc[m][n][j]));
                }
            }
    } else {
        float* Cf = (float*)Cv;
        #pragma unroll
        for (int m = 0; m < 4; ++m)
            #pragma unroll
            for (int n = 0; n < 4; ++n) {
                const int col = nt * 128 + wc * 64 + n * 16 + lr;
                #pragma unroll
                for (int j = 0; j < 4; ++j) {
                    const int row = mt * 128 + wr * 64 + m * 16 + r0 + j;
                    Cf[((size_t)e * Mpe + row) * N + col] = acc[m][n][j];
                }
            }
    }
}

extern "C" void kernel_launch(void* const* d_in, const int* in_sizes, int n_in,
                              void* d_out, int out_size, void* d_ws, size_t ws_size,
                              hipStream_t stream) {
    const float* x  = (const float*)d_in[0];   // (T, H)
    const float* w1 = (const float*)d_in[1];   // (E, F, H)
    const float* w2 = (const float*)d_in[2];   // (E, H, F)
    float* out = (float*)d_out;                // (T, H) f32

    // fp8 ws layout (bytes):
    //   [0,          67108864)  a8  : fp8 (T, F) activations (prescaled 2^13)
    //   [67108864,  100663296)  x8  : fp8 (T, H)   (prescaled 2^14)
    //   [100663296, 167772160)  w18 : fp8 (E, F, H) (prescaled 2^14)
    //   [167772160, 234881024)  w28 : fp8 (E, H, F) (prescaled 2^14)
    const size_t A8_B  = (size_t)T_TOK * F_DIM;          // 67108864
    const size_t X8_B  = (size_t)T_TOK * H_DIM;          // 33554432
    const size_t W8_B  = (size_t)E_NUM * F_DIM * H_DIM;  // 67108864
    const size_t NEED  = A8_B + X8_B + 2 * W8_B;         // 234881024

    dim3 blk(256);

    if (ws_size >= NEED) {
        u8* a8  = (u8*)d_ws;
        u8* x8  = (u8*)d_ws + A8_B;
        u8* w18 = (u8*)d_ws + A8_B + X8_B;
        u8* w28 = (u8*)d_ws + A8_B + X8_B + W8_B;

        const float SC_IN = 16384.f;   // 2^14
        cvt_f32_fp8<<<2048, blk, 0, stream>>>(x,  x8,  (long)T_TOK * H_DIM, SC_IN);
        cvt_f32_fp8<<<2048, blk, 0, stream>>>(w1, w18, (long)E_NUM * F_DIM * H_DIM, SC_IN);
        cvt_f32_fp8<<<2048, blk, 0, stream>>>(w2, w28, (long)E_NUM * H_DIM * F_DIM, SC_IN);

        // GEMM1: M=2048/exp, N=4096, K=2048 -> 8*8*16 = 1024 blocks
        const int grid1 = E_NUM * (CAPX / 256) * (F_DIM / 256);
        gemm_f8<H_DIM, true><<<grid1, dim3(512), 0, stream>>>(
            x8, w18, (void*)a8, CAPX, F_DIM, CAPX / 256, F_DIM / 256,
            3.725290298461914e-9f);   // 2^-28

        // GEMM2: M=2048/exp, N=2048, K=4096 -> 8*8*8 = 512 blocks
        const int grid2 = E_NUM * (CAPX / 256) * (H_DIM / 256);
        gemm_f8<F_DIM, false><<<grid2, dim3(512), 0, stream>>>(
            a8, w28, (void*)out, CAPX, H_DIM, CAPX / 256, H_DIM / 256,
            7.450580596923828e-9f);   // 2^-27
    } else {
        // fallback: round-1 bf16 reg-staged path (needs only bf16 a_ws)
        u16* a_ws = (u16*)d_ws;
        const int grid1 = E_NUM * (CAPX / 128) * (F_DIM / 128);
        gemm_nt<false, true><<<grid1, blk, 0, stream>>>(
            (const void*)x, w1, (void*)a_ws, CAPX, F_DIM, H_DIM,
            CAPX / 128, F_DIM / 128);

        const int grid2 = E_NUM * (CAPX / 128) * (H_DIM / 128);
        gemm_nt<true, false><<<grid2, blk, 0, stream>>>(
            (const void*)a_ws, w2, (void*)out, CAPX, H_DIM, F_DIM,
            CAPX / 128, H_DIM / 128);
    }
}

// Round 8
// 493.065 us; speedup vs baseline: 1.4383x; 1.1138x over previous
//
#include <hip/hip_runtime.h>
#include <hip/hip_bf16.h>

typedef unsigned short u16;
typedef unsigned char u8;
typedef __attribute__((ext_vector_type(8))) short bf16x8;
typedef __attribute__((ext_vector_type(4))) float f32x4;
typedef __attribute__((ext_vector_type(4))) int i32x4;
typedef __attribute__((ext_vector_type(16))) int i32x16;

#define T_TOK 16384
#define H_DIM 2048
#define F_DIM 4096
#define E_NUM 8
#define CAPX  2048   // tokens per expert

__device__ __forceinline__ unsigned cvt2(float a, float b) {
    __hip_bfloat162 h = __float22bfloat162_rn(make_float2(a, b));
    union { __hip_bfloat162 h; unsigned u; } c; c.h = h; return c.u;
}
__device__ __forceinline__ u16 f2bf(float f) {
    __hip_bfloat16 h = __float2bfloat16(f);
    union { __hip_bfloat16 h; u16 u; } c; c.h = h; return c.u;
}
__device__ __forceinline__ float gelu_tanh(float x) {
    float x3 = x * x * x;
    float z = 0.7978845608028654f * (x + 0.044715f * x3);
    float e = __expf(2.0f * z);
    float t = 1.0f - 2.0f / (e + 1.0f);   // tanh(z)
    return 0.5f * x * (1.0f + t);
}

__device__ __forceinline__ void gload_lds16(const void* g, void* l) {
    __builtin_amdgcn_global_load_lds(
        (const __attribute__((address_space(1))) void*)g,
        (__attribute__((address_space(3))) void*)l,
        16, 0, 0);
}

// ---------------------------------------------------------------------------
// f32 -> i8 conversion pre-pass (values in [0, 0.01); scale*val < 127)
// ---------------------------------------------------------------------------
__global__ void cvt_f32_i8(const float* __restrict__ in, u8* __restrict__ out,
                           long n, float s) {
    long i = (((long)blockIdx.x * blockDim.x) + threadIdx.x) << 3;
    const long stride = ((long)gridDim.x * blockDim.x) << 3;
    for (; i < n; i += stride) {
        float4 v0 = *(const float4*)(in + i);
        float4 v1 = *(const float4*)(in + i + 4);
        unsigned b0 = (unsigned)(int)(v0.x * s + 0.5f);
        unsigned b1 = (unsigned)(int)(v0.y * s + 0.5f);
        unsigned b2 = (unsigned)(int)(v0.z * s + 0.5f);
        unsigned b3 = (unsigned)(int)(v0.w * s + 0.5f);
        unsigned b4 = (unsigned)(int)(v1.x * s + 0.5f);
        unsigned b5 = (unsigned)(int)(v1.y * s + 0.5f);
        unsigned b6 = (unsigned)(int)(v1.z * s + 0.5f);
        unsigned b7 = (unsigned)(int)(v1.w * s + 0.5f);
        uint2 pk;
        pk.x = b0 | (b1 << 8) | (b2 << 16) | (b3 << 24);
        pk.y = b4 | (b5 << 8) | (b6 << 16) | (b7 << 24);
        *(uint2*)(out + i) = pk;
    }
}

// ---------------------------------------------------------------------------
// 256x256 i8 NT GEMM, 8-phase counted-vmcnt schedule (rotation verified in
// rounds 3-6 with identical LDS byte geometry).
// C[M,N] = (A_i8[M,K] @ B_i8[N,K]^T) per expert, exact i32 accumulation.
// 512 thr = 8 waves (2M x 4N); per-wave 128x64 out = acc[4][2] i32x16.
// Tile: BK=128 (i8: 128 B of K); LDS A = [buf][kh][256 rows][64 B] @0,
// B same @65536; 2 bufs -> 128 KiB. Half-tile (one kh plane) = 16 KB =
// 2 gloads/wave. K-half kh = 64 k; phase (kh, Mh) does 8 x
// mfma_i32_32x32x32_i8 (2 m-blk x 2 n-blk x 2 k-slices of 32).
// Stage rotation per ITER (tiles t->buf0, t+1->buf1):
//   p1:A1(t+1)  p2:B0(t+2) p3:A0(t+2) p4:[vmcnt(4)] B1(t+2)
//   p5:A1(t+2)  p6:B0(t+3) p7:A0(t+3) p8:[vmcnt(4)] B1(t+3)
// vmcnt(4) at p4 provably lands all 4 halves of tile t+1 before p5-p8 read
// buf1; at p8 lands all of t+2 before next-iter p1-p4 read buf0 (each VM4
// leaves exactly the 2 newest stages = 4 loads in flight).
// Swizzle: 16B-slot' = slot ^ ((row>>1)&3), both sides (rule 21) — measured
// 0 bank conflicts in rounds 3-6 with this exact geometry.
// Frag layout (i8 32x32x32, same family as the fp8 x64 verified in round 7):
// A lane l: row=l&31, 16 contiguous k at (l>>5)*16; C/D: col=lane&31,
// row=(r&3)+8*(r>>2)+4*(lane>>5).
// ---------------------------------------------------------------------------
template<int KB, bool GELU_I8_OUT>
__global__ __launch_bounds__(512, 1)
void gemm_i8(const u8* __restrict__ A, const u8* __restrict__ B,
             void* __restrict__ Cv, int Mpe, int N,
             int mtpe, int ntpe, float hscale, float oscale) {
    __shared__ uint4 lds4[8192];          // 128 KiB
    char* ldsb = (char*)lds4;

    const int tid  = threadIdx.x;
    const int lane = tid & 63;
    const int wid  = tid >> 6;
    const int wm   = wid >> 2;            // 0..1
    const int wn   = wid & 3;             // 0..3
    const int l31  = lane & 31;
    const int g1   = lane >> 5;           // k-slice sub-slot (0/1)
    const int fx   = (l31 >> 1) & 3;      // read-side swizzle key

    // XCD-aware bijective swizzle (grid % 8 == 0)
    const int nwg = gridDim.x;
    const int cpx = nwg >> 3;
    const int bid = blockIdx.x;
    const int wg  = (bid & 7) * cpx + (bid >> 3);

    const int tpe = mtpe * ntpe;
    const int e   = wg / tpe;
    const int s   = wg - e * tpe;

    // super-tile raster: 32 tiles per super-tile (4 mt x 8 nt), serpentine
    int mt, nt;
    if ((mtpe & 3) == 0 && (ntpe & 7) == 0) {
        const int nsc   = ntpe >> 3;
        const int stile = s >> 5;
        const int w     = s & 31;
        const int str_  = stile / nsc;
        int       stc_  = stile - str_ * nsc;
        if (str_ & 1) stc_ = nsc - 1 - stc_;
        mt = str_ * 4 + (w & 3);
        nt = stc_ * 8 + (w >> 2);
    } else {
        mt = s / ntpe;
        nt = s - mt * ntpe;
    }

    const u8* Abase = A + (size_t)e * Mpe * KB + (size_t)mt * 256 * KB;
    const u8* Bbase = B + (size_t)e * N   * KB + (size_t)nt * 256 * KB;

    // staging: wave writes 1024 B linear; lane -> row = tid>>2, dest slot
    // = tid&3; pre-swizzled source slot sx = (tid&3) ^ ((tid>>3)&3)
    const int srow = tid >> 2;
    const int sx   = (tid & 3) ^ ((tid >> 3) & 3);
    const u8* pA0 = Abase + (size_t)srow * KB + sx * 16;
    const u8* pA1 = Abase + (size_t)(srow + 128) * KB + sx * 16;
    const u8* pB0 = Bbase + (size_t)srow * KB + sx * 16;
    const u8* pB1 = Bbase + (size_t)(srow + 128) * KB + sx * 16;

    // read-side byte offsets
    const int sb0   = ((0 + g1) ^ fx) << 4;   // k-slice 0 within kh plane
    const int sb1   = ((2 + g1) ^ fx) << 4;   // k-slice 1
    const int aoffb = (wm * 128 + l31) << 6;
    const int boffb = 65536 + ((wn * 64 + l31) << 6);

    const int NT = KB >> 7;   // 128-k tiles: 16 (KB=2048) / 32 (KB=4096)

    i32x16 acc[4][2] = {};
    i32x4 a00, a01, a10, a11, b00, b01, b10, b11;   // [blk][k-slice]

#define STG_A(KH, BUF, DOFF) do {                                             \
    char* d_ = ldsb + (BUF) * 32768 + (KH) * 16384 + (wid << 10);             \
    gload_lds16(pA0 + (DOFF) + (KH) * 64, d_);                                \
    gload_lds16(pA1 + (DOFF) + (KH) * 64, d_ + 8192);                         \
} while (0)

#define STG_B(KH, BUF, DOFF) do {                                             \
    char* d_ = ldsb + 65536 + (BUF) * 32768 + (KH) * 16384 + (wid << 10);     \
    gload_lds16(pB0 + (DOFF) + (KH) * 64, d_);                                \
    gload_lds16(pB1 + (DOFF) + (KH) * 64, d_ + 8192);                         \
} while (0)

#define READ_A(BUF, KH, MH) do {                                              \
    const char* p_ = ldsb + (BUF) * 32768 + (KH) * 16384 + (MH) * 4096 + aoffb; \
    a00 = *(const i32x4*)(p_ + sb0);                                          \
    a01 = *(const i32x4*)(p_ + sb1);                                          \
    a10 = *(const i32x4*)(p_ + 2048 + sb0);                                   \
    a11 = *(const i32x4*)(p_ + 2048 + sb1);                                   \
} while (0)

#define READ_B(BUF, KH) do {                                                  \
    const char* p_ = ldsb + (BUF) * 32768 + (KH) * 16384 + boffb;             \
    b00 = *(const i32x4*)(p_ + sb0);                                          \
    b01 = *(const i32x4*)(p_ + sb1);                                          \
    b10 = *(const i32x4*)(p_ + 2048 + sb0);                                   \
    b11 = *(const i32x4*)(p_ + 2048 + sb1);                                   \
} while (0)

#define BARX() do { __builtin_amdgcn_sched_barrier(0);                        \
                    __builtin_amdgcn_s_barrier();                             \
                    __builtin_amdgcn_sched_barrier(0); } while (0)
#define VM4()  asm volatile("s_waitcnt vmcnt(4)" ::: "memory")

#define MFMA8(MH) do {                                                        \
    __builtin_amdgcn_s_setprio(1);                                            \
    acc[(MH)*2+0][0] = __builtin_amdgcn_mfma_i32_32x32x32_i8(a00, b00, acc[(MH)*2+0][0], 0, 0, 0); \
    acc[(MH)*2+0][0] = __builtin_amdgcn_mfma_i32_32x32x32_i8(a01, b01, acc[(MH)*2+0][0], 0, 0, 0); \
    acc[(MH)*2+0][1] = __builtin_amdgcn_mfma_i32_32x32x32_i8(a00, b10, acc[(MH)*2+0][1], 0, 0, 0); \
    acc[(MH)*2+0][1] = __builtin_amdgcn_mfma_i32_32x32x32_i8(a01, b11, acc[(MH)*2+0][1], 0, 0, 0); \
    acc[(MH)*2+1][0] = __builtin_amdgcn_mfma_i32_32x32x32_i8(a10, b00, acc[(MH)*2+1][0], 0, 0, 0); \
    acc[(MH)*2+1][0] = __builtin_amdgcn_mfma_i32_32x32x32_i8(a11, b01, acc[(MH)*2+1][0], 0, 0, 0); \
    acc[(MH)*2+1][1] = __builtin_amdgcn_mfma_i32_32x32x32_i8(a10, b10, acc[(MH)*2+1][1], 0, 0, 0); \
    acc[(MH)*2+1][1] = __builtin_amdgcn_mfma_i32_32x32x32_i8(a11, b11, acc[(MH)*2+1][1], 0, 0, 0); \
    __builtin_amdgcn_s_setprio(0);                                            \
} while (0)

#define ITER(D1, D2, D3) do {                                                  \
    /*p1*/ STG_A(1,1,(D1)); READ_A(0,0,0); READ_B(0,0); MFMA8(0); BARX();      \
    /*p2*/ STG_B(0,0,(D2)); READ_A(0,0,1);              MFMA8(1); BARX();      \
    /*p3*/ STG_A(0,0,(D2)); READ_A(0,1,0); READ_B(0,1); MFMA8(0); BARX();      \
    /*p4*/ VM4();                                                              \
           STG_B(1,0,(D2)); READ_A(0,1,1);              MFMA8(1); BARX();      \
    /*p5*/ STG_A(1,0,(D2)); READ_A(1,0,0); READ_B(1,0); MFMA8(0); BARX();      \
    /*p6*/ STG_B(0,1,(D3)); READ_A(1,0,1);              MFMA8(1); BARX();      \
    /*p7*/ STG_A(0,1,(D3)); READ_A(1,1,0); READ_B(1,1); MFMA8(0); BARX();      \
    /*p8*/ VM4();                                                              \
           STG_B(1,1,(D3)); READ_A(1,1,1);              MFMA8(1); BARX();      \
} while (0)

    // prologue: 7 half-tiles (tile0 full -> buf0, tile1 minus A1 -> buf1)
    STG_B(0, 0, 0);
    STG_A(0, 0, 0);
    STG_B(1, 0, 0);
    STG_A(1, 0, 0);
    STG_B(0, 1, 128);
    STG_A(0, 1, 128);
    STG_B(1, 1, 128);
    asm volatile("s_waitcnt vmcnt(0)" ::: "memory");
    __builtin_amdgcn_s_barrier();
    __builtin_amdgcn_sched_barrier(0);

    const int nmain = (NT >> 1) - 1;
    for (int it = 0; it < nmain; ++it) {
        ITER(128, 256, 384);
        pA0 += 256; pA1 += 256; pB0 += 256; pB1 += 256;
    }
    // peeled last iteration: dead stages clamp to delta 0 (tile t's bytes ->
    // buf0 rewrites identical values; buf1 overwrites only slots whose reads
    // drained before the preceding barrier).
    ITER(128, 0, 0);

#undef STG_A
#undef STG_B
#undef READ_A
#undef READ_B
#undef BARX
#undef VM4
#undef MFMA8
#undef ITER

    // epilogue: C/D 32x32 layout: col=lane&31, row=(r&3)+8*(r>>2)+4*(lane>>5)
    const int rbase = (lane >> 5) << 2;
    if constexpr (GELU_I8_OUT) {
        u8* Cb = (u8*)Cv;
        #pragma unroll
        for (int m = 0; m < 4; ++m)
            #pragma unroll
            for (int n = 0; n < 2; ++n) {
                const int col = nt * 256 + wn * 64 + n * 32 + l31;
                #pragma unroll
                for (int r = 0; r < 16; ++r) {
                    const int row = mt * 256 + wm * 128 + m * 32 +
                                    (r & 3) + ((r >> 2) << 3) + rbase;
                    float h = (float)acc[m][n][r] * hscale;
                    float a = gelu_tanh(h) * 1000.f + 0.5f;  // act scale 1000
                    Cb[((size_t)e * Mpe + row) * N + col] = (u8)(int)a;
                }
            }
    } else {
        float* Cf = (float*)Cv;
        #pragma unroll
        for (int m = 0; m < 4; ++m)
            #pragma unroll
            for (int n = 0; n < 2; ++n) {
                const int col = nt * 256 + wn * 64 + n * 32 + l31;
                #pragma unroll
                for (int r = 0; r < 16; ++r) {
                    const int row = mt * 256 + wm * 128 + m * 32 +
                                    (r & 3) + ((r >> 2) << 3) + rbase;
                    Cf[((size_t)e * Mpe + row) * N + col] =
                        (float)acc[m][n][r] * oscale;
                }
            }
    }
}

// ---------------------------------------------------------------------------
// FALLBACK (round-1): bf16 reg-staged with in-flight f32->bf16 conversion.
// ---------------------------------------------------------------------------
template<bool A_BF16, bool GELU_BF16_OUT>
__global__ __launch_bounds__(256, 2)
void gemm_nt(const void* __restrict__ Av, const float* __restrict__ B,
             void* __restrict__ Cv, int Mpe, int N, int K,
             int mtpe, int ntpe) {
    __shared__ u16 As[128 * 64];
    __shared__ u16 Bs[128 * 64];

    const int tid  = threadIdx.x;
    const int lane = tid & 63;
    const int w    = tid >> 6;
    const int wr   = w >> 1, wc = w & 1;
    const int lr   = lane & 15;
    const int lkb  = (lane >> 4) << 3;

    const int nwg = gridDim.x;
    const int cpx = nwg >> 3;
    const int bid = blockIdx.x;
    const int wg  = (bid & 7) * cpx + (bid >> 3);

    const int tpe = mtpe * ntpe;
    const int e   = wg / tpe;
    const int rem = wg - e * tpe;
    const int mt  = rem / ntpe;
    const int nt  = rem - mt * ntpe;

    const size_t Abase = (size_t)e * Mpe * K + (size_t)mt * 128 * K;
    const size_t Bbase = (size_t)e * N   * K + (size_t)nt * 128 * K;

    const int srow = tid >> 3;
    const int scol = (tid & 7) << 3;

    f32x4 acc[4][4] = {};

    const float* Af = (const float*)Av;
    const u16*   Ab = (const u16*)Av;

    for (int k0 = 0; k0 < K; k0 += 64) {
        #pragma unroll
        for (int p = 0; p < 4; ++p) {
            const int row = (p << 5) + srow;
            const int di  = (row << 6) + (scol ^ ((row & 7) << 3));
            if constexpr (A_BF16) {
                const u16* ap = Ab + Abase + (size_t)row * K + k0 + scol;
                *(uint4*)&As[di] = *(const uint4*)ap;
            } else {
                const float* ap = Af + Abase + (size_t)row * K + k0 + scol;
                float4 v0 = *(const float4*)ap;
                float4 v1 = *(const float4*)(ap + 4);
                uint4 pk;
                pk.x = cvt2(v0.x, v0.y); pk.y = cvt2(v0.z, v0.w);
                pk.z = cvt2(v1.x, v1.y); pk.w = cvt2(v1.z, v1.w);
                *(uint4*)&As[di] = pk;
            }
            {
                const float* bp = B + Bbase + (size_t)row * K + k0 + scol;
                float4 v0 = *(const float4*)bp;
                float4 v1 = *(const float4*)(bp + 4);
                uint4 pk;
                pk.x = cvt2(v0.x, v0.y); pk.y = cvt2(v0.z, v0.w);
                pk.z = cvt2(v1.x, v1.y); pk.w = cvt2(v1.z, v1.w);
                *(uint4*)&Bs[di] = pk;
            }
        }
        __syncthreads();

        #pragma unroll
        for (int ks = 0; ks < 2; ++ks) {
            const int kcol = (ks << 5) + lkb;
            bf16x8 af[4], bfv[4];
            #pragma unroll
            for (int m = 0; m < 4; ++m) {
                const int row = wr * 64 + m * 16 + lr;
                af[m] = *(const bf16x8*)&As[(row << 6) + (kcol ^ ((row & 7) << 3))];
            }
            #pragma unroll
            for (int n = 0; n < 4; ++n) {
                const int row = wc * 64 + n * 16 + lr;
                bfv[n] = *(const bf16x8*)&Bs[(row << 6) + (kcol ^ ((row & 7) << 3))];
            }
            #pragma unroll
            for (int m = 0; m < 4; ++m)
                #pragma unroll
                for (int n = 0; n < 4; ++n)
                    acc[m][n] = __builtin_amdgcn_mfma_f32_16x16x32_bf16(
                        af[m], bfv[n], acc[m][n], 0, 0, 0);
        }
        __syncthreads();
    }

    const int r0 = (lane >> 4) << 2;
    if constexpr (GELU_BF16_OUT) {
        u16* Cb = (u16*)Cv;
        #pragma unroll
        for (int m = 0; m < 4; ++m)
            #pragma unroll
            for (int n = 0; n < 4; ++n) {
                const int col = nt * 128 + wc * 64 + n * 16 + lr;
                #pragma unroll
                for (int j = 0; j < 4; ++j) {
                    const int row = mt * 128 + wr * 64 + m * 16 + r0 + j;
                    Cb[((size_t)e * Mpe + row) * N + col] =
                        f2bf(gelu_tanh(acc[m][n][j]));
                }
            }
    } else {
        float* Cf = (float*)Cv;
        #pragma unroll
        for (int m = 0; m < 4; ++m)
            #pragma unroll
            for (int n = 0; n < 4; ++n) {
                const int col = nt * 128 + wc * 64 + n * 16 + lr;
                #pragma unroll
                for (int j = 0; j < 4; ++j) {
                    const int row = mt * 128 + wr * 64 + m * 16 + r0 + j;
                    Cf[((size_t)e * Mpe + row) * N + col] = acc[m][n][j];
                }
            }
    }
}

extern "C" void kernel_launch(void* const* d_in, const int* in_sizes, int n_in,
                              void* d_out, int out_size, void* d_ws, size_t ws_size,
                              hipStream_t stream) {
    const float* x  = (const float*)d_in[0];   // (T, H)
    const float* w1 = (const float*)d_in[1];   // (E, F, H)
    const float* w2 = (const float*)d_in[2];   // (E, H, F)
    float* out = (float*)d_out;                // (T, H) f32

    // i8 ws layout (bytes):
    //   [0,          67108864)  a8  : i8 (T, F) activations (scale 1000)
    //   [67108864,  100663296)  x8  : i8 (T, H)   (scale 12600)
    //   [100663296, 167772160)  w18 : i8 (E, F, H) (scale 12600)
    //   [167772160, 234881024)  w28 : i8 (E, H, F) (scale 12600)
    const size_t A8_B  = (size_t)T_TOK * F_DIM;          // 67108864
    const size_t X8_B  = (size_t)T_TOK * H_DIM;          // 33554432
    const size_t W8_B  = (size_t)E_NUM * F_DIM * H_DIM;  // 67108864
    const size_t NEED  = A8_B + X8_B + 2 * W8_B;         // 234881024

    dim3 blk(256);

    if (ws_size >= NEED) {
        u8* a8  = (u8*)d_ws;
        u8* x8  = (u8*)d_ws + A8_B;
        u8* w18 = (u8*)d_ws + A8_B + X8_B;
        u8* w28 = (u8*)d_ws + A8_B + X8_B + W8_B;

        const float S1 = 12600.f;
        cvt_f32_i8<<<2048, blk, 0, stream>>>(x,  x8,  (long)T_TOK * H_DIM, S1);
        cvt_f32_i8<<<2048, blk, 0, stream>>>(w1, w18, (long)E_NUM * F_DIM * H_DIM, S1);
        cvt_f32_i8<<<2048, blk, 0, stream>>>(w2, w28, (long)E_NUM * H_DIM * F_DIM, S1);

        const float HS  = 1.f / (12600.f * 12600.f);     // GEMM1 dequant
        const float OS2 = 1.f / (1000.f * 12600.f);      // GEMM2 dequant

        // GEMM1: M=2048/exp, N=4096, K=2048 -> 8*8*16 = 1024 blocks
        const int grid1 = E_NUM * (CAPX / 256) * (F_DIM / 256);
        gemm_i8<H_DIM, true><<<grid1, dim3(512), 0, stream>>>(
            x8, w18, (void*)a8, CAPX, F_DIM, CAPX / 256, F_DIM / 256, HS, 0.f);

        // GEMM2: M=2048/exp, N=2048, K=4096 -> 8*8*8 = 512 blocks
        const int grid2 = E_NUM * (CAPX / 256) * (H_DIM / 256);
        gemm_i8<F_DIM, false><<<grid2, dim3(512), 0, stream>>>(
            a8, w28, (void*)out, CAPX, H_DIM, CAPX / 256, H_DIM / 256, 0.f, OS2);
    } else {
        // fallback: round-1 bf16 reg-staged path (needs only bf16 a_ws)
        u16* a_ws = (u16*)d_ws;
        const int grid1 = E_NUM * (CAPX / 128) * (F_DIM / 128);
        gemm_nt<false, true><<<grid1, blk, 0, stream>>>(
            (const void*)x, w1, (void*)a_ws, CAPX, F_DIM, H_DIM,
            CAPX / 128, F_DIM / 128);

        const int grid2 = E_NUM * (CAPX / 128) * (H_DIM / 128);
        gemm_nt<true, false><<<grid2, blk, 0, stream>>>(
            (const void*)a_ws, w2, (void*)out, CAPX, H_DIM, F_DIM,
            CAPX / 128, H_DIM / 128);
    }
}